// Round 1
// baseline (305.918 us; speedup 1.0000x reference)
//
#include <hip/hip_runtime.h>
#include <hip/hip_bf16.h>

#define DEVI __device__ __forceinline__

using bf16x8 = __attribute__((ext_vector_type(8))) short;
using f32x4  = __attribute__((ext_vector_type(4))) float;

DEVI unsigned short f2bf(float f){
  unsigned int u = __float_as_uint(f);
  return (unsigned short)((u + 0x7fffu + ((u>>16)&1u)) >> 16);
}

// ---------------------------------------------------------------------------
// Kernel 1: fused QKV projection.  C[m,n] = X[m,:] . W[n,:] + b[n]
// X fp32 [4096][1024], W fp32 [1024][1024] (torch Linear => NT gemm).
// Output bf16 in [b][h][s][d] layout; Q pre-scaled by 1/sqrt(D)=0.125.
// 128x128 tile, BK=64, 256 threads (4 waves, 2x2), 4x4 16x16x32 frags/wave.
// ---------------------------------------------------------------------------
__global__ __launch_bounds__(256) void proj_qkv_kernel(
  const float* __restrict__ Xq, const float* __restrict__ Xk, const float* __restrict__ Xv,
  const float* __restrict__ Wq, const float* __restrict__ Bq,
  const float* __restrict__ Wk, const float* __restrict__ Bk,
  const float* __restrict__ Wv, const float* __restrict__ Bv,
  unsigned short* __restrict__ Qo, unsigned short* __restrict__ Ko, unsigned short* __restrict__ Vo)
{
  const int p = blockIdx.y;
  const float* __restrict__ X  = (p==0)?Xq:((p==1)?Xk:Xv);
  const float* __restrict__ W  = (p==0)?Wq:((p==1)?Wk:Wv);
  const float* __restrict__ Bb = (p==0)?Bq:((p==1)?Bk:Bv);
  unsigned short* __restrict__ Out = (p==0)?Qo:((p==1)?Ko:Vo);
  const float oscale = (p==0)?0.125f:1.0f;

  const int K = 1024;
  const int tm = blockIdx.x >> 3, tn = blockIdx.x & 7;
  const int m0 = tm*128, n0 = tn*128;
  const int tid = threadIdx.x;
  const int w = tid>>6, l = tid&63;
  const int wr = w>>1, wc = w&1;
  const int lg = l>>4, lr = l&15;

  __shared__ unsigned short As[128*64];   // swizzled row-major [128][64] bf16
  __shared__ unsigned short Bs[128*64];

  f32x4 acc[4][4];
  #pragma unroll
  for (int i=0;i<4;i++)
    #pragma unroll
    for (int j=0;j<4;j++){ f32x4 z = {0.f,0.f,0.f,0.f}; acc[i][j] = z; }

  for (int kt=0; kt<K; kt+=64){
    // stage A (fp32 -> bf16), 128*64 elems, 8B LDS writes, XOR swizzle
    #pragma unroll
    for (int i=0;i<8;i++){
      int c = tid + i*256;            // 0..2047 chunks of 4 floats
      int row = c>>4, kc = c&15;
      float4 v = *(const float4*)(X + (size_t)(m0+row)*K + kt + kc*4);
      unsigned int lo = (unsigned int)f2bf(v.x) | ((unsigned int)f2bf(v.y)<<16);
      unsigned int hi = (unsigned int)f2bf(v.z) | ((unsigned int)f2bf(v.w)<<16);
      uint2 u; u.x = lo; u.y = hi;
      int byte = (kc*8) ^ ((row&7)<<4);
      *(uint2*)((char*)As + row*128 + byte) = u;
    }
    #pragma unroll
    for (int i=0;i<8;i++){
      int c = tid + i*256;
      int row = c>>4, kc = c&15;
      float4 v = *(const float4*)(W + (size_t)(n0+row)*K + kt + kc*4);
      unsigned int lo = (unsigned int)f2bf(v.x) | ((unsigned int)f2bf(v.y)<<16);
      unsigned int hi = (unsigned int)f2bf(v.z) | ((unsigned int)f2bf(v.w)<<16);
      uint2 u; u.x = lo; u.y = hi;
      int byte = (kc*8) ^ ((row&7)<<4);
      *(uint2*)((char*)Bs + row*128 + byte) = u;
    }
    __syncthreads();

    #pragma unroll
    for (int ck=0;ck<2;ck++){
      bf16x8 af[4], bfr[4];
      #pragma unroll
      for (int f=0;f<4;f++){
        int ra = wr*64 + f*16 + lr;
        af[f]  = *(const bf16x8*)((const char*)As + ra*128 + ((ck*64 + lg*16) ^ ((ra&7)<<4)));
        int rb = wc*64 + f*16 + lr;
        bfr[f] = *(const bf16x8*)((const char*)Bs + rb*128 + ((ck*64 + lg*16) ^ ((rb&7)<<4)));
      }
      #pragma unroll
      for (int fr=0;fr<4;fr++)
        #pragma unroll
        for (int fc=0;fc<4;fc++)
          acc[fr][fc] = __builtin_amdgcn_mfma_f32_16x16x32_bf16(af[fr], bfr[fc], acc[fr][fc], 0,0,0);
    }
    __syncthreads();
  }

  // epilogue: bias, scale, write bf16 to [b][h][s][d]
  #pragma unroll
  for (int fc=0;fc<4;fc++){
    int n = n0 + wc*64 + fc*16 + lr;
    float bias = Bb[n];
    int h = n>>6, d = n&63;
    #pragma unroll
    for (int fr=0;fr<4;fr++){
      #pragma unroll
      for (int r=0;r<4;r++){
        int m = m0 + wr*64 + fr*16 + lg*4 + r;
        int b = m>>11, s = m & 2047;
        float v = (acc[fr][fc][r] + bias) * oscale;
        Out[ ((size_t)((b<<4)+h)*2048 + (size_t)s)*64 + d ] = f2bf(v);
      }
    }
  }
}

// ---------------------------------------------------------------------------
// Kernel 2: causal flash attention.
// grid = 1024 blocks: (qt descending for load balance, bh).  256 thr = 4 waves,
// each wave owns 16 q-rows.  KV tile = 64.  K in LDS row-major [kv][d],
// V in LDS transposed [d][kv], both XOR-swizzled.  P goes through wave-private
// swizzled LDS to reach MFMA A-fragment layout.
// ---------------------------------------------------------------------------
__global__ __launch_bounds__(256) void attn_kernel(
  const unsigned short* __restrict__ Q, const unsigned short* __restrict__ Kb,
  const unsigned short* __restrict__ V, unsigned short* __restrict__ AO)
{
  const int idx = blockIdx.x;
  const int qt = 31 - (idx>>5);       // heavy tiles first
  const int bh = idx & 31;
  const size_t base = (size_t)bh * (2048*64);
  const int q0 = qt*64;
  const int tid = threadIdx.x, w = tid>>6, l = tid&63;
  const int lg = l>>4, lr = l&15;

  __shared__ unsigned short Ks[64*64];
  __shared__ unsigned short Vs[64*64];
  __shared__ unsigned short Ps[4*16*64];

  // Q fragments (pre-scaled by 0.125 at projection), hoisted
  bf16x8 qf0, qf1;
  {
    const unsigned short* qp = Q + base + (size_t)(q0 + w*16 + lr)*64 + lg*8;
    qf0 = *(const bf16x8*)qp;
    qf1 = *(const bf16x8*)(qp + 32);
  }
  float m_i[4], l_i[4];
  f32x4 o_acc[4];
  #pragma unroll
  for (int i=0;i<4;i++){ m_i[i] = -INFINITY; l_i[i] = 0.f; f32x4 z={0.f,0.f,0.f,0.f}; o_acc[i]=z; }

  for (int kt=0; kt<=qt; kt++){
    const int kv0 = kt*64;
    // stage K [64][64] row-major swizzled, 16B writes
    #pragma unroll
    for (int i=0;i<2;i++){
      int c = tid + i*256;           // 512 chunks of 8 bf16
      int row = c>>3, kc = c&7;
      bf16x8 v = *(const bf16x8*)(Kb + base + (size_t)(kv0+row)*64 + kc*8);
      *(bf16x8*)((char*)Ks + row*128 + ((kc*16) ^ ((row&7)<<4))) = v;
    }
    // stage V transposed: Vs[d][kv], scalar b16 writes, swizzled
    #pragma unroll
    for (int i=0;i<2;i++){
      int kvr = tid & 63;
      int d0 = (tid>>6)*8 + i*32;
      bf16x8 v = *(const bf16x8*)(V + base + (size_t)(kv0+kvr)*64 + d0);
      #pragma unroll
      for (int j=0;j<8;j++){
        int dr = d0 + j;
        *(unsigned short*)((char*)Vs + dr*128 + ((kvr*2) ^ ((dr&7)<<4))) = (unsigned short)v[j];
      }
    }
    __syncthreads();

    // QK^T: S[q(16) x kv(64)] per wave; 4 col-tiles x 2 k-chunks
    f32x4 sacc[4];
    #pragma unroll
    for (int t=0;t<4;t++){ f32x4 z={0.f,0.f,0.f,0.f}; sacc[t]=z; }
    #pragma unroll
    for (int t=0;t<4;t++){
      #pragma unroll
      for (int ck=0;ck<2;ck++){
        int rk = t*16 + lr;
        bf16x8 kf = *(const bf16x8*)((const char*)Ks + rk*128 + ((ck*64 + lg*16) ^ ((rk&7)<<4)));
        sacc[t] = __builtin_amdgcn_mfma_f32_16x16x32_bf16(ck?qf1:qf0, kf, sacc[t], 0,0,0);
      }
    }
    // causal mask on diagonal tile
    if (kt == qt){
      #pragma unroll
      for (int t=0;t<4;t++)
        #pragma unroll
        for (int i=0;i<4;i++){
          int kcol = kv0 + t*16 + lr;
          int qrow = q0 + w*16 + lg*4 + i;
          if (kcol > qrow) sacc[t][i] = -1e30f;
        }
    }
    // online softmax (row stats live on 16-lane groups: xor 1,2,4,8)
    float mt[4];
    #pragma unroll
    for (int i=0;i<4;i++) mt[i] = fmaxf(fmaxf(sacc[0][i],sacc[1][i]), fmaxf(sacc[2][i],sacc[3][i]));
    #pragma unroll
    for (int i=0;i<4;i++){
      #pragma unroll
      for (int off=1; off<16; off<<=1)
        mt[i] = fmaxf(mt[i], __shfl_xor(mt[i], off));
    }
    float sc[4], rs[4];
    #pragma unroll
    for (int i=0;i<4;i++){
      float mn = fmaxf(m_i[i], mt[i]);
      sc[i] = __expf(m_i[i] - mn);
      m_i[i] = mn;
      rs[i] = 0.f;
    }
    #pragma unroll
    for (int t=0;t<4;t++)
      #pragma unroll
      for (int i=0;i<4;i++){
        float pv = __expf(sacc[t][i] - m_i[i]);
        sacc[t][i] = pv;
        rs[i] += pv;
      }
    #pragma unroll
    for (int i=0;i<4;i++){
      #pragma unroll
      for (int off=1; off<16; off<<=1) rs[i] += __shfl_xor(rs[i], off);
      l_i[i] = l_i[i]*sc[i] + rs[i];
    }
    #pragma unroll
    for (int dt=0;dt<4;dt++)
      #pragma unroll
      for (int i=0;i<4;i++) o_acc[dt][i] *= sc[i];

    // P -> wave-private LDS (bf16, swizzled)
    unsigned short* Pw = Ps + w*1024;
    #pragma unroll
    for (int t=0;t<4;t++)
      #pragma unroll
      for (int i=0;i<4;i++){
        int pr = lg*4 + i;
        *(unsigned short*)((char*)Pw + pr*128 + ((((t*16+lr)*2)) ^ ((pr&7)<<4))) = f2bf(sacc[t][i]);
      }
    __syncthreads();

    // PV: O[q(16) x d(64)] += P[16x64] * V[64x64]
    #pragma unroll
    for (int ck=0;ck<2;ck++){
      bf16x8 pf = *(const bf16x8*)((const char*)Pw + lr*128 + ((ck*64 + lg*16) ^ ((lr&7)<<4)));
      #pragma unroll
      for (int dt=0;dt<4;dt++){
        int vr = dt*16 + lr;
        bf16x8 vf = *(const bf16x8*)((const char*)Vs + vr*128 + ((ck*64 + lg*16) ^ ((vr&7)<<4)));
        o_acc[dt] = __builtin_amdgcn_mfma_f32_16x16x32_bf16(pf, vf, o_acc[dt], 0,0,0);
      }
    }
    __syncthreads();
  }

  // epilogue: O /= l, write bf16 to [b][s][h*64+d]
  const int b = bh>>4, h = bh&15;
  #pragma unroll
  for (int i=0;i<4;i++){
    float inv = 1.0f / l_i[i];
    int s = q0 + w*16 + lg*4 + i;
    #pragma unroll
    for (int dt=0;dt<4;dt++){
      AO[ ((size_t)b*2048 + (size_t)s)*1024 + h*64 + dt*16 + lr ] = f2bf(o_acc[dt][i] * inv);
    }
  }
}

// ---------------------------------------------------------------------------
// Kernel 3: output projection.  out[m,n] = AO[m,:] . Wo[n,:] + bo[n], fp32 out.
// A is already bf16 (attention output); Wo converted fp32->bf16 in staging.
// ---------------------------------------------------------------------------
__global__ __launch_bounds__(256) void proj_out_kernel(
  const unsigned short* __restrict__ A, const float* __restrict__ W,
  const float* __restrict__ Bb, float* __restrict__ Out)
{
  const int K = 1024;
  const int tm = blockIdx.x >> 3, tn = blockIdx.x & 7;
  const int m0 = tm*128, n0 = tn*128;
  const int tid = threadIdx.x;
  const int w = tid>>6, l = tid&63;
  const int wr = w>>1, wc = w&1;
  const int lg = l>>4, lr = l&15;

  __shared__ unsigned short As[128*64];
  __shared__ unsigned short Bs[128*64];

  f32x4 acc[4][4];
  #pragma unroll
  for (int i=0;i<4;i++)
    #pragma unroll
    for (int j=0;j<4;j++){ f32x4 z = {0.f,0.f,0.f,0.f}; acc[i][j] = z; }

  for (int kt=0; kt<K; kt+=64){
    // stage A: bf16 direct, 16B chunks
    #pragma unroll
    for (int i=0;i<4;i++){
      int c = tid + i*256;          // 1024 chunks of 8 bf16
      int row = c>>3, kc = c&7;
      bf16x8 v = *(const bf16x8*)(A + (size_t)(m0+row)*K + kt + kc*8);
      *(bf16x8*)((char*)As + row*128 + ((kc*16) ^ ((row&7)<<4))) = v;
    }
    // stage B: fp32 Wo -> bf16
    #pragma unroll
    for (int i=0;i<8;i++){
      int c = tid + i*256;
      int row = c>>4, kc = c&15;
      float4 v = *(const float4*)(W + (size_t)(n0+row)*K + kt + kc*4);
      unsigned int lo = (unsigned int)f2bf(v.x) | ((unsigned int)f2bf(v.y)<<16);
      unsigned int hi = (unsigned int)f2bf(v.z) | ((unsigned int)f2bf(v.w)<<16);
      uint2 u; u.x = lo; u.y = hi;
      int byte = (kc*8) ^ ((row&7)<<4);
      *(uint2*)((char*)Bs + row*128 + byte) = u;
    }
    __syncthreads();

    #pragma unroll
    for (int ck=0;ck<2;ck++){
      bf16x8 af[4], bfr[4];
      #pragma unroll
      for (int f=0;f<4;f++){
        int ra = wr*64 + f*16 + lr;
        af[f]  = *(const bf16x8*)((const char*)As + ra*128 + ((ck*64 + lg*16) ^ ((ra&7)<<4)));
        int rb = wc*64 + f*16 + lr;
        bfr[f] = *(const bf16x8*)((const char*)Bs + rb*128 + ((ck*64 + lg*16) ^ ((rb&7)<<4)));
      }
      #pragma unroll
      for (int fr=0;fr<4;fr++)
        #pragma unroll
        for (int fc=0;fc<4;fc++)
          acc[fr][fc] = __builtin_amdgcn_mfma_f32_16x16x32_bf16(af[fr], bfr[fc], acc[fr][fc], 0,0,0);
    }
    __syncthreads();
  }

  #pragma unroll
  for (int fc=0;fc<4;fc++){
    int n = n0 + wc*64 + fc*16 + lr;
    float bias = Bb[n];
    #pragma unroll
    for (int fr=0;fr<4;fr++){
      #pragma unroll
      for (int r=0;r<4;r++){
        int m = m0 + wr*64 + fr*16 + lg*4 + r;
        Out[(size_t)m*1024 + n] = acc[fr][fc][r] + bias;
      }
    }
  }
}

// ---------------------------------------------------------------------------
extern "C" void kernel_launch(void* const* d_in, const int* in_sizes, int n_in,
                              void* d_out, int out_size, void* d_ws, size_t ws_size,
                              hipStream_t stream)
{
  const float* Xq = (const float*)d_in[0];
  const float* Xk = (const float*)d_in[1];
  const float* Xv = (const float*)d_in[2];
  // d_in[3] = mask (causal, known statically) — unused
  const float* Wq = (const float*)d_in[4];
  const float* bq = (const float*)d_in[5];
  const float* Wk = (const float*)d_in[6];
  const float* bk = (const float*)d_in[7];
  const float* Wv = (const float*)d_in[8];
  const float* bv = (const float*)d_in[9];
  const float* Wo = (const float*)d_in[10];
  const float* bo = (const float*)d_in[11];

  unsigned short* ws  = (unsigned short*)d_ws;
  unsigned short* Qw  = ws;                 // [2][16][2048][64] bf16, pre-scaled
  unsigned short* Kw  = ws + 4194304;
  unsigned short* Vw  = ws + 8388608;
  unsigned short* AOw = ws + 12582912;      // [2][2048][1024] bf16
  float* out = (float*)d_out;

  proj_qkv_kernel<<<dim3(256,3), 256, 0, stream>>>(Xq,Xk,Xv,Wq,bq,Wk,bk,Wv,bv,Qw,Kw,Vw);
  attn_kernel<<<1024, 256, 0, stream>>>(Qw,Kw,Vw,AOw);
  proj_out_kernel<<<256, 256, 0, stream>>>(AOw,Wo,bo,out);
}

// Round 3
// 262.989 us; speedup vs baseline: 1.1632x; 1.1632x over previous
//
#include <hip/hip_runtime.h>
#include <hip/hip_bf16.h>

#define DEVI __device__ __forceinline__

using bf16x8 = __attribute__((ext_vector_type(8))) short;
using f32x4  = __attribute__((ext_vector_type(4))) float;

DEVI unsigned short f2bf(float f){
  unsigned int u = __float_as_uint(f);
  return (unsigned short)((u + 0x7fffu + ((u>>16)&1u)) >> 16);
}

DEVI unsigned int cvt_pk_bf16(float lo, float hi){
  unsigned int r;
  asm("v_cvt_pk_bf16_f32 %0, %1, %2" : "=v"(r) : "v"(lo), "v"(hi));
  return r;
}

DEVI void gload_lds16(const unsigned short* src, unsigned short* lds){
  __builtin_amdgcn_global_load_lds((const __attribute__((address_space(1))) void*)src,
                                   (__attribute__((address_space(3))) void*)lds, 16, 0, 0);
}

// ---------------------------------------------------------------------------
// Kernel 0: fp32 -> bf16 convert for X (y=0..2, 4M elems) and W (y=3..6, 1M).
// ---------------------------------------------------------------------------
__global__ __launch_bounds__(256) void convert_kernel(
  const float* __restrict__ Xq, const float* __restrict__ Xk, const float* __restrict__ Xv,
  const float* __restrict__ Wq, const float* __restrict__ Wk, const float* __restrict__ Wv,
  const float* __restrict__ Wo, unsigned short* __restrict__ ws)
{
  const int y = blockIdx.y;
  const float* src;
  unsigned short* dst;
  int n4;
  if (y < 3){
    src = (y==0)?Xq:((y==1)?Xk:Xv);
    dst = ws + (size_t)y*4194304;
    n4 = 1048576;                      // 4M / 4
  } else {
    src = (y==3)?Wq:((y==4)?Wk:((y==5)?Wv:Wo));
    dst = ws + 12582912 + (size_t)(y-3)*1048576;
    n4 = 262144;                       // 1M / 4
  }
  const int stride = gridDim.x * 256;
  for (int i = blockIdx.x*256 + threadIdx.x; i < n4; i += stride){
    float4 v = ((const float4*)src)[i];
    uint2 u;
    u.x = cvt_pk_bf16(v.x, v.y);
    u.y = cvt_pk_bf16(v.z, v.w);
    ((uint2*)dst)[i] = u;
  }
}

// ---------------------------------------------------------------------------
// Kernel 1: QKV projection GEMM (m97 structure).  A,B bf16 in ws.
// C[m,n] = A[m,:].B[n,:] + bias[n]; 128x128 tile, BK=64, global_load_lds 16B,
// linear LDS.  Output bf16 [b][h][s][d], Q pre-scaled 0.125.
// ---------------------------------------------------------------------------
__global__ __launch_bounds__(256) void proj_qkv_kernel(
  const unsigned short* __restrict__ Xb, const unsigned short* __restrict__ Wb,
  const float* __restrict__ Bq, const float* __restrict__ Bk, const float* __restrict__ Bv,
  unsigned short* __restrict__ Qo, unsigned short* __restrict__ Ko, unsigned short* __restrict__ Vo)
{
  const int p = blockIdx.y;
  const unsigned short* __restrict__ A = Xb + (size_t)p*4194304;
  const unsigned short* __restrict__ B = Wb + (size_t)p*1048576;
  const float* __restrict__ Bb = (p==0)?Bq:((p==1)?Bk:Bv);
  unsigned short* __restrict__ Out = (p==0)?Qo:((p==1)?Ko:Vo);
  const float oscale = (p==0)?0.125f:1.0f;

  const int tm = blockIdx.x >> 3, tn = blockIdx.x & 7;
  const int m0 = tm*128, n0 = tn*128;
  const int tid = threadIdx.x;
  const int w = tid>>6, l = tid&63;
  const int wr = w>>1, wc = w&1;
  const int lg = l>>4, lr = l&15;

  __shared__ unsigned short As[128*64];   // linear [128][64] bf16
  __shared__ unsigned short Bs[128*64];

  f32x4 acc[4][4];
  #pragma unroll
  for (int i=0;i<4;i++)
    #pragma unroll
    for (int j=0;j<4;j++){ f32x4 z = {0.f,0.f,0.f,0.f}; acc[i][j] = z; }

  for (int kt=0; kt<1024; kt+=64){
    // stage A & B via global_load_lds: wave w covers rows [w*32, w*32+32)
    #pragma unroll
    for (int i=0;i<4;i++){
      int rbase = w*32 + i*8;
      gload_lds16(A + (size_t)(m0 + rbase + (l>>3))*1024 + kt + (l&7)*8, As + rbase*64);
      gload_lds16(B + (size_t)(n0 + rbase + (l>>3))*1024 + kt + (l&7)*8, Bs + rbase*64);
    }
    __syncthreads();

    #pragma unroll
    for (int ck=0;ck<2;ck++){
      bf16x8 af[4], bfr[4];
      #pragma unroll
      for (int f=0;f<4;f++){
        af[f]  = *(const bf16x8*)(As + (wr*64 + f*16 + lr)*64 + ck*32 + lg*8);
        bfr[f] = *(const bf16x8*)(Bs + (wc*64 + f*16 + lr)*64 + ck*32 + lg*8);
      }
      #pragma unroll
      for (int fr=0;fr<4;fr++)
        #pragma unroll
        for (int fc=0;fc<4;fc++)
          acc[fr][fc] = __builtin_amdgcn_mfma_f32_16x16x32_bf16(af[fr], bfr[fc], acc[fr][fc], 0,0,0);
    }
    __syncthreads();
  }

  #pragma unroll
  for (int fc=0;fc<4;fc++){
    int n = n0 + wc*64 + fc*16 + lr;
    float bias = Bb[n];
    int h = n>>6, d = n&63;
    #pragma unroll
    for (int fr=0;fr<4;fr++){
      #pragma unroll
      for (int r=0;r<4;r++){
        int m = m0 + wr*64 + fr*16 + lg*4 + r;
        int b = m>>11, s = m & 2047;
        float v = (acc[fr][fc][r] + bias) * oscale;
        Out[ ((size_t)((b<<4)+h)*2048 + (size_t)s)*64 + d ] = f2bf(v);
      }
    }
  }
}

// ---------------------------------------------------------------------------
// Kernel 2: causal flash attention, swapped-QK.
// 512 blocks = (16 q-tiles of 128 heavy-first) x 32 bh.  4 waves, 32 q/wave.
// KV tile 64.  S^T = mfma(K, Q): lane lr = q, rows = kv -> in-lane softmax,
// 2 shuffles/row-reduce.  P packed via v_cvt_pk_bf16 into wave-private
// swizzled LDS (no barrier), PV computes O^T = mfma(V^T, P).
// ---------------------------------------------------------------------------
__global__ __launch_bounds__(256) void attn_kernel(
  const unsigned short* __restrict__ Q, const unsigned short* __restrict__ Kb,
  const unsigned short* __restrict__ V, unsigned short* __restrict__ AO)
{
  const int idx = blockIdx.x;
  const int qt = 15 - (idx >> 5);       // heavy tiles first
  const int bh = idx & 31;
  const size_t base = (size_t)bh * (2048*64);
  const int q0 = qt * 128;
  const int tid = threadIdx.x, w = tid>>6, l = tid&63;
  const int lg = l>>4, lr = l&15;

  __shared__ unsigned short Ks[64*64];     // [kv][d] swizzled
  __shared__ unsigned short Vs[64*64];     // [d][kv] swizzled (transposed)
  __shared__ unsigned short Ps[4*32*64];   // per-wave [32 q][64 kv] swizzled
  unsigned short* Pw = Ps + w*2048;

  // hoisted Q B-frags: qf[qh][ck], q = q0 + w*32 + qh*16 + lr
  bf16x8 qf[2][2];
  #pragma unroll
  for (int qh=0; qh<2; qh++){
    const unsigned short* qp = Q + base + (size_t)(q0 + w*32 + qh*16 + lr)*64 + lg*8;
    qf[qh][0] = *(const bf16x8*)qp;
    qf[qh][1] = *(const bf16x8*)(qp + 32);
  }

  float m_i[2], l_i[2];
  f32x4 o_acc[2][4];
  #pragma unroll
  for (int qh=0;qh<2;qh++){
    m_i[qh] = -INFINITY; l_i[qh] = 0.f;
    #pragma unroll
    for (int dt=0;dt<4;dt++){ f32x4 z={0.f,0.f,0.f,0.f}; o_acc[qh][dt]=z; }
  }

  const int NT = 2*qt + 2;
  for (int kt=0; kt<NT; kt++){
    const int kv0 = kt*64;
    // stage K [64][64] swizzled, 16B writes, coalesced loads
    #pragma unroll
    for (int i=0;i<2;i++){
      int c = tid + i*256;
      int row = c>>3, kc = c&7;
      bf16x8 kv = *(const bf16x8*)(Kb + base + (size_t)(kv0+row)*64 + kc*8);
      *(bf16x8*)((char*)Ks + row*128 + ((kc*16) ^ ((row&7)<<4))) = kv;
    }
    // stage V transposed: Vs[d][kv]
    #pragma unroll
    for (int i=0;i<2;i++){
      int d0 = w*8 + i*32;
      bf16x8 vv = *(const bf16x8*)(V + base + (size_t)(kv0+l)*64 + d0);
      #pragma unroll
      for (int j=0;j<8;j++){
        int dr = d0 + j;
        *(unsigned short*)((char*)Vs + dr*128 + ((l*2) ^ ((dr&7)<<4))) = (unsigned short)vv[j];
      }
    }
    __syncthreads();

    // K A-frags, shared across both q-halves
    bf16x8 kf[4][2];
    #pragma unroll
    for (int t=0;t<4;t++){
      int rk = t*16 + lr;
      #pragma unroll
      for (int ck=0;ck<2;ck++)
        kf[t][ck] = *(const bf16x8*)((const char*)Ks + rk*128 + ((ck*64 + lg*16) ^ ((rk&7)<<4)));
    }

    #pragma unroll
    for (int qh=0; qh<2; qh++){
      f32x4 sacc[4];
      #pragma unroll
      for (int t=0;t<4;t++){ f32x4 z={0.f,0.f,0.f,0.f}; sacc[t]=z; }
      #pragma unroll
      for (int t=0;t<4;t++){
        sacc[t] = __builtin_amdgcn_mfma_f32_16x16x32_bf16(kf[t][0], qf[qh][0], sacc[t], 0,0,0);
        sacc[t] = __builtin_amdgcn_mfma_f32_16x16x32_bf16(kf[t][1], qf[qh][1], sacc[t], 0,0,0);
      }
      const int qq = q0 + w*32 + qh*16 + lr;
      if (kv0 + 63 > q0 + w*32 + qh*16){           // tile touches/passes diagonal
        #pragma unroll
        for (int t=0;t<4;t++)
          #pragma unroll
          for (int r=0;r<4;r++){
            int kvv = kv0 + t*16 + lg*4 + r;
            if (kvv > qq) sacc[t][r] = -1e30f;
          }
      }
      // softmax: row is lane-local over 16 regs + 2 shuffles across lg
      float mt = sacc[0][0];
      #pragma unroll
      for (int t=0;t<4;t++)
        #pragma unroll
        for (int r=0;r<4;r++) mt = fmaxf(mt, sacc[t][r]);
      mt = fmaxf(mt, __shfl_xor(mt, 16));
      mt = fmaxf(mt, __shfl_xor(mt, 32));
      float mn = fmaxf(m_i[qh], mt);
      float sc = __expf(m_i[qh] - mn);
      m_i[qh] = mn;
      float rs = 0.f;
      #pragma unroll
      for (int t=0;t<4;t++)
        #pragma unroll
        for (int r=0;r<4;r++){
          float pv = __expf(sacc[t][r] - mn);
          sacc[t][r] = pv;
          rs += pv;
        }
      rs += __shfl_xor(rs, 16);
      rs += __shfl_xor(rs, 32);
      l_i[qh] = l_i[qh]*sc + rs;
      #pragma unroll
      for (int dt=0;dt<4;dt++)
        #pragma unroll
        for (int r=0;r<4;r++) o_acc[qh][dt][r] *= sc;

      // pack P -> wave-private LDS row (no barrier needed: same-wave RAW)
      const int prow = qh*16 + lr;
      char* pbase = (char*)Pw + prow*128;
      const int swz = (prow&7)<<4;
      #pragma unroll
      for (int t=0;t<4;t++){
        unsigned int u01 = cvt_pk_bf16(sacc[t][0], sacc[t][1]);
        unsigned int u23 = cvt_pk_bf16(sacc[t][2], sacc[t][3]);
        *(unsigned int*)(pbase + ((32*t + 8*lg    ) ^ swz)) = u01;
        *(unsigned int*)(pbase + ((32*t + 8*lg + 4) ^ swz)) = u23;
      }
    }

    // PV: O^T[d][q] += V^T[d][kv] . P[q][kv]
    bf16x8 vt[4][2];
    #pragma unroll
    for (int dt=0;dt<4;dt++){
      int rv = dt*16 + lr;
      #pragma unroll
      for (int ck=0;ck<2;ck++)
        vt[dt][ck] = *(const bf16x8*)((const char*)Vs + rv*128 + ((ck*64 + lg*16) ^ ((rv&7)<<4)));
    }
    #pragma unroll
    for (int qh=0; qh<2; qh++){
      const int prow = qh*16 + lr;
      const int swz = (prow&7)<<4;
      #pragma unroll
      for (int ck=0;ck<2;ck++){
        bf16x8 pb = *(const bf16x8*)((const char*)Pw + prow*128 + ((ck*64 + lg*16) ^ swz));
        #pragma unroll
        for (int dt=0;dt<4;dt++)
          o_acc[qh][dt] = __builtin_amdgcn_mfma_f32_16x16x32_bf16(vt[dt][ck], pb, o_acc[qh][dt], 0,0,0);
      }
    }
    __syncthreads();
  }

  // epilogue: O[q][d] = O^T / l, 8B packed stores to [b][s][h*64+d]
  const int b = bh>>4, h = bh&15;
  #pragma unroll
  for (int qh=0;qh<2;qh++){
    float inv = 1.0f / l_i[qh];
    int q = q0 + w*32 + qh*16 + lr;
    #pragma unroll
    for (int dt=0;dt<4;dt++){
      uint2 u;
      u.x = cvt_pk_bf16(o_acc[qh][dt][0]*inv, o_acc[qh][dt][1]*inv);
      u.y = cvt_pk_bf16(o_acc[qh][dt][2]*inv, o_acc[qh][dt][3]*inv);
      *(uint2*)(AO + ((size_t)b*2048 + q)*1024 + h*64 + dt*16 + lg*4) = u;
    }
  }
}

// ---------------------------------------------------------------------------
// Kernel 3: output projection (m97 structure), fp32 out + bias.
// ---------------------------------------------------------------------------
__global__ __launch_bounds__(256) void proj_out_kernel(
  const unsigned short* __restrict__ A, const unsigned short* __restrict__ B,
  const float* __restrict__ Bb, float* __restrict__ Out)
{
  const int tm = blockIdx.x >> 3, tn = blockIdx.x & 7;
  const int m0 = tm*128, n0 = tn*128;
  const int tid = threadIdx.x;
  const int w = tid>>6, l = tid&63;
  const int wr = w>>1, wc = w&1;
  const int lg = l>>4, lr = l&15;

  __shared__ unsigned short As[128*64];
  __shared__ unsigned short Bs[128*64];

  f32x4 acc[4][4];
  #pragma unroll
  for (int i=0;i<4;i++)
    #pragma unroll
    for (int j=0;j<4;j++){ f32x4 z = {0.f,0.f,0.f,0.f}; acc[i][j] = z; }

  for (int kt=0; kt<1024; kt+=64){
    #pragma unroll
    for (int i=0;i<4;i++){
      int rbase = w*32 + i*8;
      gload_lds16(A + (size_t)(m0 + rbase + (l>>3))*1024 + kt + (l&7)*8, As + rbase*64);
      gload_lds16(B + (size_t)(n0 + rbase + (l>>3))*1024 + kt + (l&7)*8, Bs + rbase*64);
    }
    __syncthreads();

    #pragma unroll
    for (int ck=0;ck<2;ck++){
      bf16x8 af[4], bfr[4];
      #pragma unroll
      for (int f=0;f<4;f++){
        af[f]  = *(const bf16x8*)(As + (wr*64 + f*16 + lr)*64 + ck*32 + lg*8);
        bfr[f] = *(const bf16x8*)(Bs + (wc*64 + f*16 + lr)*64 + ck*32 + lg*8);
      }
      #pragma unroll
      for (int fr=0;fr<4;fr++)
        #pragma unroll
        for (int fc=0;fc<4;fc++)
          acc[fr][fc] = __builtin_amdgcn_mfma_f32_16x16x32_bf16(af[fr], bfr[fc], acc[fr][fc], 0,0,0);
    }
    __syncthreads();
  }

  #pragma unroll
  for (int fc=0;fc<4;fc++){
    int n = n0 + wc*64 + fc*16 + lr;
    float bias = Bb[n];
    #pragma unroll
    for (int fr=0;fr<4;fr++){
      #pragma unroll
      for (int r=0;r<4;r++){
        int m = m0 + wr*64 + fr*16 + lg*4 + r;
        Out[(size_t)m*1024 + n] = acc[fr][fc][r] + bias;
      }
    }
  }
}

// ---------------------------------------------------------------------------
extern "C" void kernel_launch(void* const* d_in, const int* in_sizes, int n_in,
                              void* d_out, int out_size, void* d_ws, size_t ws_size,
                              hipStream_t stream)
{
  const float* Xq = (const float*)d_in[0];
  const float* Xk = (const float*)d_in[1];
  const float* Xv = (const float*)d_in[2];
  // d_in[3] = mask (causal, static) — unused
  const float* Wq = (const float*)d_in[4];
  const float* bq = (const float*)d_in[5];
  const float* Wk = (const float*)d_in[6];
  const float* bk = (const float*)d_in[7];
  const float* Wv = (const float*)d_in[8];
  const float* bv = (const float*)d_in[9];
  const float* Wo = (const float*)d_in[10];
  const float* bo = (const float*)d_in[11];

  unsigned short* ws  = (unsigned short*)d_ws;
  // layout (ushort offsets): Xb[3x4M]@0, Wb[4x1M]@12582912,
  // Q@16777216, K@20971520, V@25165824, AO@29360128  (total 64 MB)
  unsigned short* Xb  = ws;
  unsigned short* Wb  = ws + 12582912;
  unsigned short* Qw  = ws + 16777216;
  unsigned short* Kw  = ws + 20971520;
  unsigned short* Vw  = ws + 25165824;
  unsigned short* AOw = ws + 29360128;
  float* out = (float*)d_out;

  convert_kernel<<<dim3(512,7), 256, 0, stream>>>(Xq,Xk,Xv,Wq,Wk,Wv,Wo, ws);
  proj_qkv_kernel<<<dim3(256,3), 256, 0, stream>>>(Xb, Wb, bq,bk,bv, Qw,Kw,Vw);
  attn_kernel<<<512, 256, 0, stream>>>(Qw,Kw,Vw,AOw);
  proj_out_kernel<<<256, 256, 0, stream>>>(AOw, Wb + 3*1048576, bo, out);
}

// Round 4
// 254.739 us; speedup vs baseline: 1.2009x; 1.0324x over previous
//
#include <hip/hip_runtime.h>
#include <hip/hip_bf16.h>

#define DEVI __device__ __forceinline__

using bf16x8 = __attribute__((ext_vector_type(8))) short;
using f32x4  = __attribute__((ext_vector_type(4))) float;
using f32x16 = __attribute__((ext_vector_type(16))) float;

#define LOG2E 1.4426950408889634f

DEVI unsigned short f2bf(float f){
  unsigned int u = __float_as_uint(f);
  return (unsigned short)((u + 0x7fffu + ((u>>16)&1u)) >> 16);
}

DEVI unsigned int cvt_pk_bf16(float lo, float hi){
  unsigned int r;
  asm("v_cvt_pk_bf16_f32 %0, %1, %2" : "=v"(r) : "v"(lo), "v"(hi));
  return r;
}

#if __has_builtin(__builtin_amdgcn_exp2f)
#define EXP2(x) __builtin_amdgcn_exp2f(x)
#else
#define EXP2(x) exp2f(x)
#endif

DEVI void gload_lds16(const unsigned short* src, unsigned short* lds){
  __builtin_amdgcn_global_load_lds((const __attribute__((address_space(1))) void*)src,
                                   (__attribute__((address_space(3))) void*)lds, 16, 0, 0);
}

DEVI bf16x8 mk8(unsigned w0, unsigned w1, unsigned w2, unsigned w3){
  union { unsigned u[4]; bf16x8 v; } x;
  x.u[0]=w0; x.u[1]=w1; x.u[2]=w2; x.u[3]=w3;
  return x.v;
}

// ---------------------------------------------------------------------------
// Kernel 0: fp32 -> bf16 convert for X (y=0..2, 4M elems) and W (y=3..6, 1M).
// ---------------------------------------------------------------------------
__global__ __launch_bounds__(256) void convert_kernel(
  const float* __restrict__ Xq, const float* __restrict__ Xk, const float* __restrict__ Xv,
  const float* __restrict__ Wq, const float* __restrict__ Wk, const float* __restrict__ Wv,
  const float* __restrict__ Wo, unsigned short* __restrict__ ws)
{
  const int y = blockIdx.y;
  const float* src;
  unsigned short* dst;
  int n4;
  if (y < 3){
    src = (y==0)?Xq:((y==1)?Xk:Xv);
    dst = ws + (size_t)y*4194304;
    n4 = 1048576;
  } else {
    src = (y==3)?Wq:((y==4)?Wk:((y==5)?Wv:Wo));
    dst = ws + 12582912 + (size_t)(y-3)*1048576;
    n4 = 262144;
  }
  const int stride = gridDim.x * 256;
  for (int i = blockIdx.x*256 + threadIdx.x; i < n4; i += stride){
    float4 v = ((const float4*)src)[i];
    uint2 u;
    u.x = cvt_pk_bf16(v.x, v.y);
    u.y = cvt_pk_bf16(v.z, v.w);
    ((uint2*)dst)[i] = u;
  }
}

// ---------------------------------------------------------------------------
// Kernel 1: QKV projection GEMM (m97 structure).  A,B bf16 in ws.
// 128x128 tile, BK=64, global_load_lds 16B, linear LDS.
// Q out: [b][h][s][d], pre-scaled by 0.125*log2e (exp2-domain softmax).
// K out: [b][h][s][d].   V out: TRANSPOSED [b][h][d][s].
// ---------------------------------------------------------------------------
__global__ __launch_bounds__(256) void proj_qkv_kernel(
  const unsigned short* __restrict__ Xb, const unsigned short* __restrict__ Wb,
  const float* __restrict__ Bq, const float* __restrict__ Bk, const float* __restrict__ Bv,
  unsigned short* __restrict__ Qo, unsigned short* __restrict__ Ko, unsigned short* __restrict__ Vo)
{
  const int p = blockIdx.y;
  const unsigned short* __restrict__ A = Xb + (size_t)p*4194304;
  const unsigned short* __restrict__ B = Wb + (size_t)p*1048576;
  const float* __restrict__ Bb = (p==0)?Bq:((p==1)?Bk:Bv);
  unsigned short* __restrict__ Out = (p==0)?Qo:((p==1)?Ko:Vo);
  const float oscale = (p==0)?(0.125f*LOG2E):1.0f;

  const int tm = blockIdx.x >> 3, tn = blockIdx.x & 7;
  const int m0 = tm*128, n0 = tn*128;
  const int tid = threadIdx.x;
  const int w = tid>>6, l = tid&63;
  const int wr = w>>1, wc = w&1;
  const int lg = l>>4, lr = l&15;

  __shared__ unsigned short As[128*64];
  __shared__ unsigned short Bs[128*64];

  f32x4 acc[4][4];
  #pragma unroll
  for (int i=0;i<4;i++)
    #pragma unroll
    for (int j=0;j<4;j++){ f32x4 z = {0.f,0.f,0.f,0.f}; acc[i][j] = z; }

  for (int kt=0; kt<1024; kt+=64){
    #pragma unroll
    for (int i=0;i<4;i++){
      int rbase = w*32 + i*8;
      gload_lds16(A + (size_t)(m0 + rbase + (l>>3))*1024 + kt + (l&7)*8, As + rbase*64);
      gload_lds16(B + (size_t)(n0 + rbase + (l>>3))*1024 + kt + (l&7)*8, Bs + rbase*64);
    }
    __syncthreads();

    #pragma unroll
    for (int ck=0;ck<2;ck++){
      bf16x8 af[4], bfr[4];
      #pragma unroll
      for (int f=0;f<4;f++){
        af[f]  = *(const bf16x8*)(As + (wr*64 + f*16 + lr)*64 + ck*32 + lg*8);
        bfr[f] = *(const bf16x8*)(Bs + (wc*64 + f*16 + lr)*64 + ck*32 + lg*8);
      }
      #pragma unroll
      for (int fr=0;fr<4;fr++)
        #pragma unroll
        for (int fc=0;fc<4;fc++)
          acc[fr][fc] = __builtin_amdgcn_mfma_f32_16x16x32_bf16(af[fr], bfr[fc], acc[fr][fc], 0,0,0);
    }
    __syncthreads();
  }

  if (p == 2){
    // V^T output: [b][h][d][s]; per (fc,fr) lane stores 4 consecutive s as uint2
    #pragma unroll
    for (int fc=0;fc<4;fc++){
      int n = n0 + wc*64 + fc*16 + lr;
      float bias = Bb[n];
      int h = n>>6, d = n&63;
      #pragma unroll
      for (int fr=0;fr<4;fr++){
        int m = m0 + wr*64 + fr*16 + lg*4;
        int b = m>>11, s = m & 2047;
        uint2 u;
        u.x = cvt_pk_bf16(acc[fr][fc][0]+bias, acc[fr][fc][1]+bias);
        u.y = cvt_pk_bf16(acc[fr][fc][2]+bias, acc[fr][fc][3]+bias);
        *(uint2*)(Out + (((size_t)((b<<4)+h)*64 + d)*2048 + s)) = u;
      }
    }
  } else {
    #pragma unroll
    for (int fc=0;fc<4;fc++){
      int n = n0 + wc*64 + fc*16 + lr;
      float bias = Bb[n];
      int h = n>>6, d = n&63;
      #pragma unroll
      for (int fr=0;fr<4;fr++){
        #pragma unroll
        for (int r=0;r<4;r++){
          int m = m0 + wr*64 + fr*16 + lg*4 + r;
          int b = m>>11, s = m & 2047;
          float v = (acc[fr][fc][r] + bias) * oscale;
          Out[ ((size_t)((b<<4)+h)*2048 + (size_t)s)*64 + d ] = f2bf(v);
        }
      }
    }
  }
}

// ---------------------------------------------------------------------------
// Kernel 2: causal flash attention, 32x32x16 MFMA, fully in-register softmax/P.
// 512 blocks = (16 q-tiles of 128, heavy-first) x 32 bh.  4 waves x 32 q-rows.
// KVBLK=64.  S^T = mfma(K, Q^T): lane owns one q-column -> in-lane softmax.
// P stays in registers (cvt_pk + shfl_xor(32) + cndmask) -> PV B-operand.
// K and V^T staged via global_load_lds (linear LDS, source-XOR-swizzled),
// double-buffered, stage-before-compute.  exp2-domain (log2e pre-folded in Q).
// ---------------------------------------------------------------------------
__global__ __launch_bounds__(256,2) void attn_kernel(
  const unsigned short* __restrict__ Q, const unsigned short* __restrict__ Kg,
  const unsigned short* __restrict__ Vt, unsigned short* __restrict__ AO)
{
  const int idx = blockIdx.x;
  const int qt = 15 - (idx >> 5);       // heavy tiles first
  const int bh = idx & 31;
  const size_t base = (size_t)bh * 131072;   // 2048*64
  const int q0 = qt * 128;
  const int tid = threadIdx.x, w = tid>>6, l = tid&63;
  const int lq = l & 31, hi = l >> 5;
  const int qq = q0 + w*32 + lq;

  __shared__ unsigned short Ks[2][4096];   // [kv][d] swizzled (src-side XOR)
  __shared__ unsigned short Vs[2][4096];   // [d][kv] swizzled

  // hoisted Q B-frags: qf[s] = Q[qq][s*16 + hi*8 .. +8]
  bf16x8 qf[4];
  {
    const unsigned short* qp = Q + base + (size_t)qq*64;
    #pragma unroll
    for (int s=0;s<4;s++) qf[s] = *(const bf16x8*)(qp + s*16 + hi*8);
  }

  f32x16 oacc[2];
  #pragma unroll
  for (int dt=0;dt<2;dt++)
    #pragma unroll
    for (int r=0;r<16;r++) oacc[dt][r] = 0.f;
  float m_i = -INFINITY, l_i = 0.f;

  const int NT = 2*qt + 2;

  // stage helper (as lambda): tile kt -> buffer half
  auto stage = [&](int kt, int half){
    const int kv0 = kt*64;
    #pragma unroll
    for (int i=0;i<2;i++){
      int c = tid + i*256;              // 512 chunks of 16B per tile
      int row = c>>3;
      int kc = (c&7) ^ (row&7);         // inverse swizzle on the SOURCE
      gload_lds16(Kg + base + (size_t)(kv0+row)*64 + kc*8, &Ks[half][0] + c*8);
      gload_lds16(Vt + base + (size_t)row*2048 + kv0 + kc*8, &Vs[half][0] + c*8);
    }
  };

  stage(0, 0);
  __syncthreads();

  for (int kt=0; kt<NT; kt++){
    const int cur = kt & 1;
    if (kt+1 < NT) stage(kt+1, cur^1);
    const int kv0 = kt*64;

    // ---- QK^T: S^T[kv 64][q 32], 2 kv-subtiles of 32
    f32x16 sacc[2];
    #pragma unroll
    for (int kvt=0;kvt<2;kvt++)
      #pragma unroll
      for (int r=0;r<16;r++) sacc[kvt][r] = 0.f;

    __builtin_amdgcn_s_setprio(1);
    #pragma unroll
    for (int kvt=0;kvt<2;kvt++){
      int row = kvt*32 + lq;
      const char* kb = (const char*)&Ks[cur][0] + row*128;
      int swz = (row&7)<<4;
      #pragma unroll
      for (int s=0;s<4;s++){
        bf16x8 kf = *(const bf16x8*)(kb + ((s*32 + hi*16) ^ swz));
        sacc[kvt] = __builtin_amdgcn_mfma_f32_32x32x16_bf16(kf, qf[s], sacc[kvt], 0,0,0);
      }
    }
    __builtin_amdgcn_s_setprio(0);

    // ---- causal mask (boundary tiles only)
    #pragma unroll
    for (int kvt=0;kvt<2;kvt++){
      if (kv0 + kvt*32 + 31 > q0 + w*32){
        #pragma unroll
        for (int r=0;r<16;r++){
          int kvv = kv0 + kvt*32 + (r&3) + 8*(r>>2) + 4*hi;
          if (kvv > qq) sacc[kvt][r] = -1e30f;
        }
      }
    }

    // ---- online softmax (exp2 domain), lane owns column qq
    float mt = sacc[0][0];
    #pragma unroll
    for (int kvt=0;kvt<2;kvt++)
      #pragma unroll
      for (int r=0;r<16;r++) mt = fmaxf(mt, sacc[kvt][r]);
    mt = fmaxf(mt, __shfl_xor(mt, 32));

    if (__any(mt > m_i + 8.f)){          // defer-max (T13)
      float mn = fmaxf(m_i, mt);
      float sc = EXP2(m_i - mn);
      m_i = mn;
      l_i *= sc;
      #pragma unroll
      for (int dt=0;dt<2;dt++)
        #pragma unroll
        for (int r=0;r<16;r++) oacc[dt][r] *= sc;
    }
    float rs = 0.f;
    #pragma unroll
    for (int kvt=0;kvt<2;kvt++)
      #pragma unroll
      for (int r=0;r<16;r++){
        float pv = EXP2(sacc[kvt][r] - m_i);
        sacc[kvt][r] = pv;
        rs += pv;
      }
    rs += __shfl_xor(rs, 32);
    l_i += rs;

    // ---- pack P to bf16 in-register, exchange lane<->lane+32
    // grp g (kvt=g>>2, gl=g&3): rows 8*gl + 4*hi + {0..3} of subtile kvt
    unsigned pa[8], pb[8], sa[8], sb[8];
    #pragma unroll
    for (int g=0; g<8; g++){
      int kvt = g>>2, gl = g&3;
      pa[g] = cvt_pk_bf16(sacc[kvt][4*gl+0], sacc[kvt][4*gl+1]);
      pb[g] = cvt_pk_bf16(sacc[kvt][4*gl+2], sacc[kvt][4*gl+3]);
      sa[g] = __shfl_xor(pa[g], 32);
      sb[g] = __shfl_xor(pb[g], 32);
    }
    bf16x8 pfrag[4];
    #pragma unroll
    for (int s=0;s<4;s++){
      int g0 = (s>>1)*4 + 2*(s&1);
      unsigned w0 = hi ? sa[g0+1] : pa[g0];
      unsigned w1 = hi ? sb[g0+1] : pb[g0];
      unsigned w2 = hi ? pa[g0+1] : sa[g0];
      unsigned w3 = hi ? pb[g0+1] : sb[g0];
      pfrag[s] = mk8(w0, w1, w2, w3);
    }

    // ---- PV: O^T[d][q] += V^T[d][kv] . P^T[kv][q]
    __builtin_amdgcn_s_setprio(1);
    #pragma unroll
    for (int dt=0;dt<2;dt++){
      int row = dt*32 + lq;
      const char* vb = (const char*)&Vs[cur][0] + row*128;
      int swz = (row&7)<<4;
      #pragma unroll
      for (int s=0;s<4;s++){
        bf16x8 vf = *(const bf16x8*)(vb + ((s*32 + hi*16) ^ swz));
        oacc[dt] = __builtin_amdgcn_mfma_f32_32x32x16_bf16(vf, pfrag[s], oacc[dt], 0,0,0);
      }
    }
    __builtin_amdgcn_s_setprio(0);

    __syncthreads();   // drains stage(kt+1) vmcnt + guards buffer reuse
  }

  // ---- epilogue: O^T -> LDS transpose (wave-private) -> coalesced AO stores
  unsigned short* Es = &Ks[0][0] + w*2048;   // 32 q-rows x 64 d, swizzled
  float inv = 1.0f / l_i;
  {
    char* eb = (char*)Es + lq*128;
    int swz = (lq&7)<<4;
    #pragma unroll
    for (int dt=0;dt<2;dt++)
      #pragma unroll
      for (int g=0;g<4;g++){
        int d0 = dt*32 + 8*g + 4*hi;
        unsigned u0 = cvt_pk_bf16(oacc[dt][4*g+0]*inv, oacc[dt][4*g+1]*inv);
        unsigned u1 = cvt_pk_bf16(oacc[dt][4*g+2]*inv, oacc[dt][4*g+3]*inv);
        *(unsigned*)(eb + ((d0*2    ) ^ swz)) = u0;
        *(unsigned*)(eb + ((d0*2 + 4) ^ swz)) = u1;
      }
  }
  // same-wave readback (compiler inserts lgkmcnt)
  const int b = bh>>4, h = bh&15;
  {
    const char* rb = (const char*)Es + lq*128;
    int swz = (lq&7)<<4;
    unsigned short* op = AO + ((size_t)b*2048 + (q0 + w*32 + lq))*1024 + h*64 + hi*32;
    #pragma unroll
    for (int j=0;j<2;j++){
      bf16x8 v = *(const bf16x8*)(rb + ((hi*64 + j*16) ^ swz));
      *(bf16x8*)(op + j*8) = v;
    }
    #pragma unroll
    for (int j=2;j<4;j++){
      bf16x8 v = *(const bf16x8*)(rb + ((hi*64 + j*16) ^ swz));
      *(bf16x8*)(op + j*8) = v;
    }
  }
}

// ---------------------------------------------------------------------------
// Kernel 3: output projection (m97 structure), fp32 out + bias.
// ---------------------------------------------------------------------------
__global__ __launch_bounds__(256) void proj_out_kernel(
  const unsigned short* __restrict__ A, const unsigned short* __restrict__ B,
  const float* __restrict__ Bb, float* __restrict__ Out)
{
  const int tm = blockIdx.x >> 3, tn = blockIdx.x & 7;
  const int m0 = tm*128, n0 = tn*128;
  const int tid = threadIdx.x;
  const int w = tid>>6, l = tid&63;
  const int wr = w>>1, wc = w&1;
  const int lg = l>>4, lr = l&15;

  __shared__ unsigned short As[128*64];
  __shared__ unsigned short Bs[128*64];

  f32x4 acc[4][4];
  #pragma unroll
  for (int i=0;i<4;i++)
    #pragma unroll
    for (int j=0;j<4;j++){ f32x4 z = {0.f,0.f,0.f,0.f}; acc[i][j] = z; }

  for (int kt=0; kt<1024; kt+=64){
    #pragma unroll
    for (int i=0;i<4;i++){
      int rbase = w*32 + i*8;
      gload_lds16(A + (size_t)(m0 + rbase + (l>>3))*1024 + kt + (l&7)*8, As + rbase*64);
      gload_lds16(B + (size_t)(n0 + rbase + (l>>3))*1024 + kt + (l&7)*8, Bs + rbase*64);
    }
    __syncthreads();

    #pragma unroll
    for (int ck=0;ck<2;ck++){
      bf16x8 af[4], bfr[4];
      #pragma unroll
      for (int f=0;f<4;f++){
        af[f]  = *(const bf16x8*)(As + (wr*64 + f*16 + lr)*64 + ck*32 + lg*8);
        bfr[f] = *(const bf16x8*)(Bs + (wc*64 + f*16 + lr)*64 + ck*32 + lg*8);
      }
      #pragma unroll
      for (int fr=0;fr<4;fr++)
        #pragma unroll
        for (int fc=0;fc<4;fc++)
          acc[fr][fc] = __builtin_amdgcn_mfma_f32_16x16x32_bf16(af[fr], bfr[fc], acc[fr][fc], 0,0,0);
    }
    __syncthreads();
  }

  #pragma unroll
  for (int fc=0;fc<4;fc++){
    int n = n0 + wc*64 + fc*16 + lr;
    float bias = Bb[n];
    #pragma unroll
    for (int fr=0;fr<4;fr++){
      #pragma unroll
      for (int r=0;r<4;r++){
        int m = m0 + wr*64 + fr*16 + lg*4 + r;
        Out[(size_t)m*1024 + n] = acc[fr][fc][r] + bias;
      }
    }
  }
}

// ---------------------------------------------------------------------------
extern "C" void kernel_launch(void* const* d_in, const int* in_sizes, int n_in,
                              void* d_out, int out_size, void* d_ws, size_t ws_size,
                              hipStream_t stream)
{
  const float* Xq = (const float*)d_in[0];
  const float* Xk = (const float*)d_in[1];
  const float* Xv = (const float*)d_in[2];
  // d_in[3] = mask (causal, static) — unused
  const float* Wq = (const float*)d_in[4];
  const float* bq = (const float*)d_in[5];
  const float* Wk = (const float*)d_in[6];
  const float* bk = (const float*)d_in[7];
  const float* Wv = (const float*)d_in[8];
  const float* bv = (const float*)d_in[9];
  const float* Wo = (const float*)d_in[10];
  const float* bo = (const float*)d_in[11];

  unsigned short* ws  = (unsigned short*)d_ws;
  // layout (ushort offsets): Xb[3x4M]@0, Wb[4x1M]@12582912,
  // Q@16777216, K@20971520, V^T@25165824, AO@29360128  (total 64 MB)
  unsigned short* Xb  = ws;
  unsigned short* Wb  = ws + 12582912;
  unsigned short* Qw  = ws + 16777216;
  unsigned short* Kw  = ws + 20971520;
  unsigned short* Vw  = ws + 25165824;
  unsigned short* AOw = ws + 29360128;
  float* out = (float*)d_out;

  convert_kernel<<<dim3(512,7), 256, 0, stream>>>(Xq,Xk,Xv,Wq,Wk,Wv,Wo, ws);
  proj_qkv_kernel<<<dim3(256,3), 256, 0, stream>>>(Xb, Wb, bq,bk,bv, Qw,Kw,Vw);
  attn_kernel<<<512, 256, 0, stream>>>(Qw,Kw,Vw,AOw);
  proj_out_kernel<<<256, 256, 0, stream>>>(AOw, Wb + 3*1048576, bo, out);
}

// Round 5
// 249.170 us; speedup vs baseline: 1.2277x; 1.0223x over previous
//
#include <hip/hip_runtime.h>
#include <hip/hip_bf16.h>

#define DEVI __device__ __forceinline__

using bf16x8 = __attribute__((ext_vector_type(8))) short;
using f32x4  = __attribute__((ext_vector_type(4))) float;
using f32x16 = __attribute__((ext_vector_type(16))) float;

#define LOG2E 1.4426950408889634f

DEVI unsigned short f2bf(float f){
  unsigned int u = __float_as_uint(f);
  return (unsigned short)((u + 0x7fffu + ((u>>16)&1u)) >> 16);
}

DEVI unsigned int cvt_pk_bf16(float lo, float hi){
  unsigned int r;
  asm("v_cvt_pk_bf16_f32 %0, %1, %2" : "=v"(r) : "v"(lo), "v"(hi));
  return r;
}

#if __has_builtin(__builtin_amdgcn_exp2f)
#define EXP2(x) __builtin_amdgcn_exp2f(x)
#else
#define EXP2(x) exp2f(x)
#endif

DEVI void gload_lds16(const unsigned short* src, unsigned short* lds){
  __builtin_amdgcn_global_load_lds((const __attribute__((address_space(1))) void*)src,
                                   (__attribute__((address_space(3))) void*)lds, 16, 0, 0);
}

DEVI bf16x8 mk8(unsigned w0, unsigned w1, unsigned w2, unsigned w3){
  union { unsigned u[4]; bf16x8 v; } x;
  x.u[0]=w0; x.u[1]=w1; x.u[2]=w2; x.u[3]=w3;
  return x.v;
}

// ---------------------------------------------------------------------------
// Kernel 0: fp32 -> bf16 convert for X (y=0..2, 4M elems) and W (y=3..6, 1M).
// ---------------------------------------------------------------------------
__global__ __launch_bounds__(256) void convert_kernel(
  const float* __restrict__ Xq, const float* __restrict__ Xk, const float* __restrict__ Xv,
  const float* __restrict__ Wq, const float* __restrict__ Wk, const float* __restrict__ Wv,
  const float* __restrict__ Wo, unsigned short* __restrict__ ws)
{
  const int y = blockIdx.y;
  const float* src;
  unsigned short* dst;
  int n4;
  if (y < 3){
    src = (y==0)?Xq:((y==1)?Xk:Xv);
    dst = ws + (size_t)y*4194304;
    n4 = 1048576;
  } else {
    src = (y==3)?Wq:((y==4)?Wk:((y==5)?Wv:Wo));
    dst = ws + 12582912 + (size_t)(y-3)*1048576;
    n4 = 262144;
  }
  const int stride = gridDim.x * 256;
  for (int i = blockIdx.x*256 + threadIdx.x; i < n4; i += stride){
    float4 v = ((const float4*)src)[i];
    uint2 u;
    u.x = cvt_pk_bf16(v.x, v.y);
    u.y = cvt_pk_bf16(v.z, v.w);
    ((uint2*)dst)[i] = u;
  }
}

// ---------------------------------------------------------------------------
// Kernel 1: QKV projection GEMM.  128x128 tile, BK=64, 2-phase double-buffered
// pipeline (T3 minimum): stage(t+1) at top, one vmcnt(0)+barrier per K-step.
// T2: source-XOR-swizzled global_load_lds (linear dest) + swizzled ds_read.
// T1: XCD-grouped block map — each XCD owns 12 contiguous (p,tm) A-panels.
// Q out [b][h][s][d] scaled 0.125*log2e; K out [b][h][s][d]; V out [b][h][d][s].
// ---------------------------------------------------------------------------
__global__ __launch_bounds__(256) void proj_qkv_kernel(
  const unsigned short* __restrict__ Xb, const unsigned short* __restrict__ Wb,
  const float* __restrict__ Bq, const float* __restrict__ Bk, const float* __restrict__ Bv,
  unsigned short* __restrict__ Qo, unsigned short* __restrict__ Ko, unsigned short* __restrict__ Vo)
{
  // XCD-aware mapping: L -> (p, tm, tn).  768 blocks, 8 XCDs, 96 per XCD.
  const int L = blockIdx.x;
  const int xcd = L & 7, g = L >> 3;
  const int combo = xcd*12 + (g>>3);     // (p,tm) combo, 12 per XCD
  const int tn = g & 7;
  const int p  = combo >> 5;
  const int tm = combo & 31;

  const unsigned short* __restrict__ A = Xb + (size_t)p*4194304;
  const unsigned short* __restrict__ B = Wb + (size_t)p*1048576;
  const float* __restrict__ Bb = (p==0)?Bq:((p==1)?Bk:Bv);
  unsigned short* __restrict__ Out = (p==0)?Qo:((p==1)?Ko:Vo);
  const float oscale = (p==0)?(0.125f*LOG2E):1.0f;

  const int m0 = tm*128, n0 = tn*128;
  const int tid = threadIdx.x;
  const int w = tid>>6, l = tid&63;
  const int wr = w>>1, wc = w&1;
  const int lg = l>>4, lr = l&15;

  __shared__ unsigned short As[2][8192];   // [128][64] bf16, chunk-swizzled
  __shared__ unsigned short Bs[2][8192];

  f32x4 acc[4][4];
  #pragma unroll
  for (int i=0;i<4;i++)
    #pragma unroll
    for (int j=0;j<4;j++){ f32x4 z = {0.f,0.f,0.f,0.f}; acc[i][j] = z; }

  // stage: lane l covers row rbase+(l>>3), chunk (l&7); source chunk is
  // XOR-permuted by row&7 (= l>>3 since rbase%8==0) -> swizzled layout in LDS.
  const int sub = l>>3;
  const int kc  = (l&7) ^ sub;
  auto stage = [&](int kt, int h){
    #pragma unroll
    for (int i=0;i<4;i++){
      int rbase = w*32 + i*8;
      gload_lds16(A + (size_t)(m0+rbase+sub)*1024 + kt + kc*8, &As[h][0] + rbase*64);
      gload_lds16(B + (size_t)(n0+rbase+sub)*1024 + kt + kc*8, &Bs[h][0] + rbase*64);
    }
  };

  stage(0, 0);
  asm volatile("s_waitcnt vmcnt(0)" ::: "memory");
  __builtin_amdgcn_s_barrier();

  int cur = 0;
  for (int kt6=0; kt6<16; kt6++){
    if (kt6 < 15) stage((kt6+1)*64, cur^1);

    #pragma unroll
    for (int ck=0;ck<2;ck++){
      bf16x8 af[4], bfr[4];
      #pragma unroll
      for (int f=0;f<4;f++){
        int ra = wr*64 + f*16 + lr;
        af[f]  = *(const bf16x8*)((const char*)&As[cur][0] + ra*128 + ((ck*64 + lg*16) ^ ((ra&7)<<4)));
        int rb = wc*64 + f*16 + lr;
        bfr[f] = *(const bf16x8*)((const char*)&Bs[cur][0] + rb*128 + ((ck*64 + lg*16) ^ ((rb&7)<<4)));
      }
      #pragma unroll
      for (int fr=0;fr<4;fr++)
        #pragma unroll
        for (int fc=0;fc<4;fc++)
          acc[fr][fc] = __builtin_amdgcn_mfma_f32_16x16x32_bf16(af[fr], bfr[fc], acc[fr][fc], 0,0,0);
    }

    asm volatile("s_waitcnt vmcnt(0)" ::: "memory");
    __builtin_amdgcn_s_barrier();
    cur ^= 1;
  }

  if (p == 2){
    // V^T output: [b][h][d][s]
    #pragma unroll
    for (int fc=0;fc<4;fc++){
      int n = n0 + wc*64 + fc*16 + lr;
      float bias = Bb[n];
      int h = n>>6, d = n&63;
      #pragma unroll
      for (int fr=0;fr<4;fr++){
        int m = m0 + wr*64 + fr*16 + lg*4;
        int b = m>>11, s = m & 2047;
        uint2 u;
        u.x = cvt_pk_bf16(acc[fr][fc][0]+bias, acc[fr][fc][1]+bias);
        u.y = cvt_pk_bf16(acc[fr][fc][2]+bias, acc[fr][fc][3]+bias);
        *(uint2*)(Out + (((size_t)((b<<4)+h)*64 + d)*2048 + s)) = u;
      }
    }
  } else {
    #pragma unroll
    for (int fc=0;fc<4;fc++){
      int n = n0 + wc*64 + fc*16 + lr;
      float bias = Bb[n];
      int h = n>>6, d = n&63;
      #pragma unroll
      for (int fr=0;fr<4;fr++){
        #pragma unroll
        for (int r=0;r<4;r++){
          int m = m0 + wr*64 + fr*16 + lg*4 + r;
          int b = m>>11, s = m & 2047;
          float v = (acc[fr][fc][r] + bias) * oscale;
          Out[ ((size_t)((b<<4)+h)*2048 + (size_t)s)*64 + d ] = f2bf(v);
        }
      }
    }
  }
}

// ---------------------------------------------------------------------------
// Kernel 2: causal flash attention, 32x32x16 MFMA, fully in-register softmax/P.
// (unchanged from round 3 — validated)
// ---------------------------------------------------------------------------
__global__ __launch_bounds__(256,2) void attn_kernel(
  const unsigned short* __restrict__ Q, const unsigned short* __restrict__ Kg,
  const unsigned short* __restrict__ Vt, unsigned short* __restrict__ AO)
{
  const int idx = blockIdx.x;
  const int qt = 15 - (idx >> 5);       // heavy tiles first
  const int bh = idx & 31;
  const size_t base = (size_t)bh * 131072;   // 2048*64
  const int q0 = qt * 128;
  const int tid = threadIdx.x, w = tid>>6, l = tid&63;
  const int lq = l & 31, hi = l >> 5;
  const int qq = q0 + w*32 + lq;

  __shared__ unsigned short Ks[2][4096];   // [kv][d] swizzled (src-side XOR)
  __shared__ unsigned short Vs[2][4096];   // [d][kv] swizzled

  bf16x8 qf[4];
  {
    const unsigned short* qp = Q + base + (size_t)qq*64;
    #pragma unroll
    for (int s=0;s<4;s++) qf[s] = *(const bf16x8*)(qp + s*16 + hi*8);
  }

  f32x16 oacc[2];
  #pragma unroll
  for (int dt=0;dt<2;dt++)
    #pragma unroll
    for (int r=0;r<16;r++) oacc[dt][r] = 0.f;
  float m_i = -INFINITY, l_i = 0.f;

  const int NT = 2*qt + 2;

  auto stage = [&](int kt, int half){
    const int kv0 = kt*64;
    #pragma unroll
    for (int i=0;i<2;i++){
      int c = tid + i*256;
      int row = c>>3;
      int kc = (c&7) ^ (row&7);
      gload_lds16(Kg + base + (size_t)(kv0+row)*64 + kc*8, &Ks[half][0] + c*8);
      gload_lds16(Vt + base + (size_t)row*2048 + kv0 + kc*8, &Vs[half][0] + c*8);
    }
  };

  stage(0, 0);
  __syncthreads();

  for (int kt=0; kt<NT; kt++){
    const int cur = kt & 1;
    if (kt+1 < NT) stage(kt+1, cur^1);
    const int kv0 = kt*64;

    f32x16 sacc[2];
    #pragma unroll
    for (int kvt=0;kvt<2;kvt++)
      #pragma unroll
      for (int r=0;r<16;r++) sacc[kvt][r] = 0.f;

    __builtin_amdgcn_s_setprio(1);
    #pragma unroll
    for (int kvt=0;kvt<2;kvt++){
      int row = kvt*32 + lq;
      const char* kb = (const char*)&Ks[cur][0] + row*128;
      int swz = (row&7)<<4;
      #pragma unroll
      for (int s=0;s<4;s++){
        bf16x8 kf = *(const bf16x8*)(kb + ((s*32 + hi*16) ^ swz));
        sacc[kvt] = __builtin_amdgcn_mfma_f32_32x32x16_bf16(kf, qf[s], sacc[kvt], 0,0,0);
      }
    }
    __builtin_amdgcn_s_setprio(0);

    #pragma unroll
    for (int kvt=0;kvt<2;kvt++){
      if (kv0 + kvt*32 + 31 > q0 + w*32){
        #pragma unroll
        for (int r=0;r<16;r++){
          int kvv = kv0 + kvt*32 + (r&3) + 8*(r>>2) + 4*hi;
          if (kvv > qq) sacc[kvt][r] = -1e30f;
        }
      }
    }

    float mt = sacc[0][0];
    #pragma unroll
    for (int kvt=0;kvt<2;kvt++)
      #pragma unroll
      for (int r=0;r<16;r++) mt = fmaxf(mt, sacc[kvt][r]);
    mt = fmaxf(mt, __shfl_xor(mt, 32));

    if (__any(mt > m_i + 8.f)){
      float mn = fmaxf(m_i, mt);
      float sc = EXP2(m_i - mn);
      m_i = mn;
      l_i *= sc;
      #pragma unroll
      for (int dt=0;dt<2;dt++)
        #pragma unroll
        for (int r=0;r<16;r++) oacc[dt][r] *= sc;
    }
    float rs = 0.f;
    #pragma unroll
    for (int kvt=0;kvt<2;kvt++)
      #pragma unroll
      for (int r=0;r<16;r++){
        float pv = EXP2(sacc[kvt][r] - m_i);
        sacc[kvt][r] = pv;
        rs += pv;
      }
    rs += __shfl_xor(rs, 32);
    l_i += rs;

    unsigned pa[8], pb[8], sa[8], sb[8];
    #pragma unroll
    for (int g=0; g<8; g++){
      int kvt = g>>2, gl = g&3;
      pa[g] = cvt_pk_bf16(sacc[kvt][4*gl+0], sacc[kvt][4*gl+1]);
      pb[g] = cvt_pk_bf16(sacc[kvt][4*gl+2], sacc[kvt][4*gl+3]);
      sa[g] = __shfl_xor(pa[g], 32);
      sb[g] = __shfl_xor(pb[g], 32);
    }
    bf16x8 pfrag[4];
    #pragma unroll
    for (int s=0;s<4;s++){
      int g0 = (s>>1)*4 + 2*(s&1);
      unsigned w0 = hi ? sa[g0+1] : pa[g0];
      unsigned w1 = hi ? sb[g0+1] : pb[g0];
      unsigned w2 = hi ? pa[g0+1] : sa[g0];
      unsigned w3 = hi ? pb[g0+1] : sb[g0];
      pfrag[s] = mk8(w0, w1, w2, w3);
    }

    __builtin_amdgcn_s_setprio(1);
    #pragma unroll
    for (int dt=0;dt<2;dt++){
      int row = dt*32 + lq;
      const char* vb = (const char*)&Vs[cur][0] + row*128;
      int swz = (row&7)<<4;
      #pragma unroll
      for (int s=0;s<4;s++){
        bf16x8 vf = *(const bf16x8*)(vb + ((s*32 + hi*16) ^ swz));
        oacc[dt] = __builtin_amdgcn_mfma_f32_32x32x16_bf16(vf, pfrag[s], oacc[dt], 0,0,0);
      }
    }
    __builtin_amdgcn_s_setprio(0);

    __syncthreads();
  }

  unsigned short* Es = &Ks[0][0] + w*2048;
  float inv = 1.0f / l_i;
  {
    char* eb = (char*)Es + lq*128;
    int swz = (lq&7)<<4;
    #pragma unroll
    for (int dt=0;dt<2;dt++)
      #pragma unroll
      for (int g=0;g<4;g++){
        int d0 = dt*32 + 8*g + 4*hi;
        unsigned u0 = cvt_pk_bf16(oacc[dt][4*g+0]*inv, oacc[dt][4*g+1]*inv);
        unsigned u1 = cvt_pk_bf16(oacc[dt][4*g+2]*inv, oacc[dt][4*g+3]*inv);
        *(unsigned*)(eb + ((d0*2    ) ^ swz)) = u0;
        *(unsigned*)(eb + ((d0*2 + 4) ^ swz)) = u1;
      }
  }
  const int b = bh>>4, h = bh&15;
  {
    const char* rb = (const char*)Es + lq*128;
    int swz = (lq&7)<<4;
    unsigned short* op = AO + ((size_t)b*2048 + (q0 + w*32 + lq))*1024 + h*64 + hi*32;
    #pragma unroll
    for (int j=0;j<2;j++){
      bf16x8 v = *(const bf16x8*)(rb + ((hi*64 + j*16) ^ swz));
      *(bf16x8*)(op + j*8) = v;
    }
    #pragma unroll
    for (int j=2;j<4;j++){
      bf16x8 v = *(const bf16x8*)(rb + ((hi*64 + j*16) ^ swz));
      *(bf16x8*)(op + j*8) = v;
    }
  }
}

// ---------------------------------------------------------------------------
// Kernel 3: output projection — same 2-phase + T2 + XCD-map structure.
// fp32 out + bias.
// ---------------------------------------------------------------------------
__global__ __launch_bounds__(256) void proj_out_kernel(
  const unsigned short* __restrict__ A, const unsigned short* __restrict__ B,
  const float* __restrict__ Bb, float* __restrict__ Out)
{
  const int L = blockIdx.x;             // 256 blocks
  const int xcd = L & 7, g = L >> 3;
  const int tm = xcd*4 + (g>>3);
  const int tn = g & 7;
  const int m0 = tm*128, n0 = tn*128;
  const int tid = threadIdx.x;
  const int w = tid>>6, l = tid&63;
  const int wr = w>>1, wc = w&1;
  const int lg = l>>4, lr = l&15;

  __shared__ unsigned short As[2][8192];
  __shared__ unsigned short Bs[2][8192];

  f32x4 acc[4][4];
  #pragma unroll
  for (int i=0;i<4;i++)
    #pragma unroll
    for (int j=0;j<4;j++){ f32x4 z = {0.f,0.f,0.f,0.f}; acc[i][j] = z; }

  const int sub = l>>3;
  const int kc  = (l&7) ^ sub;
  auto stage = [&](int kt, int h){
    #pragma unroll
    for (int i=0;i<4;i++){
      int rbase = w*32 + i*8;
      gload_lds16(A + (size_t)(m0+rbase+sub)*1024 + kt + kc*8, &As[h][0] + rbase*64);
      gload_lds16(B + (size_t)(n0+rbase+sub)*1024 + kt + kc*8, &Bs[h][0] + rbase*64);
    }
  };

  stage(0, 0);
  asm volatile("s_waitcnt vmcnt(0)" ::: "memory");
  __builtin_amdgcn_s_barrier();

  int cur = 0;
  for (int kt6=0; kt6<16; kt6++){
    if (kt6 < 15) stage((kt6+1)*64, cur^1);

    #pragma unroll
    for (int ck=0;ck<2;ck++){
      bf16x8 af[4], bfr[4];
      #pragma unroll
      for (int f=0;f<4;f++){
        int ra = wr*64 + f*16 + lr;
        af[f]  = *(const bf16x8*)((const char*)&As[cur][0] + ra*128 + ((ck*64 + lg*16) ^ ((ra&7)<<4)));
        int rb = wc*64 + f*16 + lr;
        bfr[f] = *(const bf16x8*)((const char*)&Bs[cur][0] + rb*128 + ((ck*64 + lg*16) ^ ((rb&7)<<4)));
      }
      #pragma unroll
      for (int fr=0;fr<4;fr++)
        #pragma unroll
        for (int fc=0;fc<4;fc++)
          acc[fr][fc] = __builtin_amdgcn_mfma_f32_16x16x32_bf16(af[fr], bfr[fc], acc[fr][fc], 0,0,0);
    }

    asm volatile("s_waitcnt vmcnt(0)" ::: "memory");
    __builtin_amdgcn_s_barrier();
    cur ^= 1;
  }

  #pragma unroll
  for (int fc=0;fc<4;fc++){
    int n = n0 + wc*64 + fc*16 + lr;
    float bias = Bb[n];
    #pragma unroll
    for (int fr=0;fr<4;fr++){
      #pragma unroll
      for (int r=0;r<4;r++){
        int m = m0 + wr*64 + fr*16 + lg*4 + r;
        Out[(size_t)m*1024 + n] = acc[fr][fc][r] + bias;
      }
    }
  }
}

// ---------------------------------------------------------------------------
extern "C" void kernel_launch(void* const* d_in, const int* in_sizes, int n_in,
                              void* d_out, int out_size, void* d_ws, size_t ws_size,
                              hipStream_t stream)
{
  const float* Xq = (const float*)d_in[0];
  const float* Xk = (const float*)d_in[1];
  const float* Xv = (const float*)d_in[2];
  // d_in[3] = mask (causal, static) — unused
  const float* Wq = (const float*)d_in[4];
  const float* bq = (const float*)d_in[5];
  const float* Wk = (const float*)d_in[6];
  const float* bk = (const float*)d_in[7];
  const float* Wv = (const float*)d_in[8];
  const float* bv = (const float*)d_in[9];
  const float* Wo = (const float*)d_in[10];
  const float* bo = (const float*)d_in[11];

  unsigned short* ws  = (unsigned short*)d_ws;
  unsigned short* Xb  = ws;
  unsigned short* Wb  = ws + 12582912;
  unsigned short* Qw  = ws + 16777216;
  unsigned short* Kw  = ws + 20971520;
  unsigned short* Vw  = ws + 25165824;
  unsigned short* AOw = ws + 29360128;
  float* out = (float*)d_out;

  convert_kernel<<<dim3(512,7), 256, 0, stream>>>(Xq,Xk,Xv,Wq,Wk,Wv,Wo, ws);
  proj_qkv_kernel<<<768, 256, 0, stream>>>(Xb, Wb, bq,bk,bv, Qw,Kw,Vw);
  attn_kernel<<<512, 256, 0, stream>>>(Qw,Kw,Vw,AOw);
  proj_out_kernel<<<256, 256, 0, stream>>>(AOw, Wb + 3*1048576, bo, out);
}

// Round 6
// 235.544 us; speedup vs baseline: 1.2988x; 1.0578x over previous
//
#include <hip/hip_runtime.h>
#include <hip/hip_bf16.h>

#define DEVI __device__ __forceinline__

using bf16x8 = __attribute__((ext_vector_type(8))) short;
using f32x4  = __attribute__((ext_vector_type(4))) float;
using f32x16 = __attribute__((ext_vector_type(16))) float;

#define LOG2E 1.4426950408889634f

DEVI unsigned short f2bf(float f){
  unsigned int u = __float_as_uint(f);
  return (unsigned short)((u + 0x7fffu + ((u>>16)&1u)) >> 16);
}

DEVI unsigned int cvt_pk_bf16(float lo, float hi){
  unsigned int r;
  asm("v_cvt_pk_bf16_f32 %0, %1, %2" : "=v"(r) : "v"(lo), "v"(hi));
  return r;
}

#if __has_builtin(__builtin_amdgcn_exp2f)
#define EXP2(x) __builtin_amdgcn_exp2f(x)
#else
#define EXP2(x) exp2f(x)
#endif

DEVI void gload_lds16(const unsigned short* src, unsigned short* lds){
  __builtin_amdgcn_global_load_lds((const __attribute__((address_space(1))) void*)src,
                                   (__attribute__((address_space(3))) void*)lds, 16, 0, 0);
}

DEVI bf16x8 mk8(unsigned w0, unsigned w1, unsigned w2, unsigned w3){
  union { unsigned u[4]; bf16x8 v; } x;
  x.u[0]=w0; x.u[1]=w1; x.u[2]=w2; x.u[3]=w3;
  return x.v;
}

// ---------------------------------------------------------------------------
// Kernel 0: fp32 -> bf16 convert for X (y=0..2, 4M elems) and W (y=3..6, 1M).
// ---------------------------------------------------------------------------
__global__ __launch_bounds__(256) void convert_kernel(
  const float* __restrict__ Xq, const float* __restrict__ Xk, const float* __restrict__ Xv,
  const float* __restrict__ Wq, const float* __restrict__ Wk, const float* __restrict__ Wv,
  const float* __restrict__ Wo, unsigned short* __restrict__ ws)
{
  const int y = blockIdx.y;
  const float* src;
  unsigned short* dst;
  int n4;
  if (y < 3){
    src = (y==0)?Xq:((y==1)?Xk:Xv);
    dst = ws + (size_t)y*4194304;
    n4 = 1048576;
  } else {
    src = (y==3)?Wq:((y==4)?Wk:((y==5)?Wv:Wo));
    dst = ws + 12582912 + (size_t)(y-3)*1048576;
    n4 = 262144;
  }
  const int stride = gridDim.x * 256;
  for (int i = blockIdx.x*256 + threadIdx.x; i < n4; i += stride){
    float4 v = ((const float4*)src)[i];
    uint2 u;
    u.x = cvt_pk_bf16(v.x, v.y);
    u.y = cvt_pk_bf16(v.z, v.w);
    ((uint2*)dst)[i] = u;
  }
}

// ---------------------------------------------------------------------------
// Kernel 1: QKV projection GEMM.  128x128 tile, BK=32 half-steps, 3 LDS
// buffers (48 KB -> 3 blocks/CU), depth-2 prefetch with COUNTED vmcnt(4)
// (T4: never drain to 0 in main loop).  Order per step: vmcnt(4) -> barrier
// -> issue stage(h+2) -> compute(h).  chunk^=(row&3) source-side swizzle.
// T1 XCD map.  Q out [b][h][s][d] scaled 0.125*log2e; K [b][h][s][d];
// V TRANSPOSED [b][h][d][s].
// ---------------------------------------------------------------------------
__global__ __launch_bounds__(256, 3) void proj_qkv_kernel(
  const unsigned short* __restrict__ Xb, const unsigned short* __restrict__ Wb,
  const float* __restrict__ Bq, const float* __restrict__ Bk, const float* __restrict__ Bv,
  unsigned short* __restrict__ Qo, unsigned short* __restrict__ Ko, unsigned short* __restrict__ Vo)
{
  // XCD-aware mapping: 768 blocks, 8 XCDs, 96 per XCD; each XCD owns 12 (p,tm).
  const int L = blockIdx.x;
  const int xcd = L & 7, g = L >> 3;
  const int combo = xcd*12 + (g>>3);
  const int tn = g & 7;
  const int p  = combo >> 5;
  const int tm = combo & 31;

  const unsigned short* __restrict__ A = Xb + (size_t)p*4194304;
  const unsigned short* __restrict__ B = Wb + (size_t)p*1048576;
  const float* __restrict__ Bb = (p==0)?Bq:((p==1)?Bk:Bv);
  unsigned short* __restrict__ Out = (p==0)?Qo:((p==1)?Ko:Vo);
  const float oscale = (p==0)?(0.125f*LOG2E):1.0f;

  const int m0 = tm*128, n0 = tn*128;
  const int tid = threadIdx.x;
  const int w = tid>>6, l = tid&63;
  const int wr = w>>1, wc = w&1;
  const int lg = l>>4, lr = l&15;

  __shared__ unsigned short As[3][4096];   // [128][32] bf16, chunk-swizzled
  __shared__ unsigned short Bs[3][4096];

  f32x4 acc[4][4];
  #pragma unroll
  for (int i=0;i<4;i++)
    #pragma unroll
    for (int j=0;j<4;j++){ f32x4 z = {0.f,0.f,0.f,0.f}; acc[i][j] = z; }

  // stage: lane l -> row rbase+(l>>2), LDS chunk (l&3); source chunk XOR row&3.
  const int srow = l>>2;
  const int schk = (l&3) ^ (srow&3);
  auto stage = [&](int h, int buf){
    const int kt = h*32;
    #pragma unroll
    for (int i=0;i<2;i++){
      int rbase = w*32 + i*16;
      gload_lds16(A + (size_t)(m0+rbase+srow)*1024 + kt + schk*8, &As[buf][0] + rbase*32);
      gload_lds16(B + (size_t)(n0+rbase+srow)*1024 + kt + schk*8, &Bs[buf][0] + rbase*32);
    }
  };

  stage(0, 0);
  stage(1, 1);

  const int sca = (lg ^ (lr&3)) << 4;   // lane-constant read swizzle (bytes)
  int cur = 0;
  for (int h=0; h<32; ++h){
    if (h < 31) asm volatile("s_waitcnt vmcnt(4)" ::: "memory");
    else        asm volatile("s_waitcnt vmcnt(0)" ::: "memory");
    __builtin_amdgcn_s_barrier();
    __builtin_amdgcn_sched_barrier(0);
    if (h < 30){
      int nb = cur + 2; if (nb >= 3) nb -= 3;
      stage(h+2, nb);
    }

    bf16x8 af[4], bfr[4];
    #pragma unroll
    for (int f=0;f<4;f++){
      af[f]  = *(const bf16x8*)((const char*)&As[cur][0] + (wr*64 + f*16 + lr)*64 + sca);
      bfr[f] = *(const bf16x8*)((const char*)&Bs[cur][0] + (wc*64 + f*16 + lr)*64 + sca);
    }
    #pragma unroll
    for (int fr=0;fr<4;fr++)
      #pragma unroll
      for (int fc=0;fc<4;fc++)
        acc[fr][fc] = __builtin_amdgcn_mfma_f32_16x16x32_bf16(af[fr], bfr[fc], acc[fr][fc], 0,0,0);

    cur = (cur==2) ? 0 : cur+1;
  }

  if (p == 2){
    // V^T output: [b][h][d][s]
    #pragma unroll
    for (int fc=0;fc<4;fc++){
      int n = n0 + wc*64 + fc*16 + lr;
      float bias = Bb[n];
      int h = n>>6, d = n&63;
      #pragma unroll
      for (int fr=0;fr<4;fr++){
        int m = m0 + wr*64 + fr*16 + lg*4;
        int b = m>>11, s = m & 2047;
        uint2 u;
        u.x = cvt_pk_bf16(acc[fr][fc][0]+bias, acc[fr][fc][1]+bias);
        u.y = cvt_pk_bf16(acc[fr][fc][2]+bias, acc[fr][fc][3]+bias);
        *(uint2*)(Out + (((size_t)((b<<4)+h)*64 + d)*2048 + s)) = u;
      }
    }
  } else {
    #pragma unroll
    for (int fc=0;fc<4;fc++){
      int n = n0 + wc*64 + fc*16 + lr;
      float bias = Bb[n];
      int h = n>>6, d = n&63;
      #pragma unroll
      for (int fr=0;fr<4;fr++){
        #pragma unroll
        for (int r=0;r<4;r++){
          int m = m0 + wr*64 + fr*16 + lg*4 + r;
          int b = m>>11, s = m & 2047;
          float v = (acc[fr][fc][r] + bias) * oscale;
          Out[ ((size_t)((b<<4)+h)*2048 + (size_t)s)*64 + d ] = f2bf(v);
        }
      }
    }
  }
}

// ---------------------------------------------------------------------------
// Kernel 2: causal flash attention, 32x32x16 MFMA, fully in-register softmax/P.
// (unchanged — validated)
// ---------------------------------------------------------------------------
__global__ __launch_bounds__(256,2) void attn_kernel(
  const unsigned short* __restrict__ Q, const unsigned short* __restrict__ Kg,
  const unsigned short* __restrict__ Vt, unsigned short* __restrict__ AO)
{
  const int idx = blockIdx.x;
  const int qt = 15 - (idx >> 5);       // heavy tiles first
  const int bh = idx & 31;
  const size_t base = (size_t)bh * 131072;   // 2048*64
  const int q0 = qt * 128;
  const int tid = threadIdx.x, w = tid>>6, l = tid&63;
  const int lq = l & 31, hi = l >> 5;
  const int qq = q0 + w*32 + lq;

  __shared__ unsigned short Ks[2][4096];   // [kv][d] swizzled (src-side XOR)
  __shared__ unsigned short Vs[2][4096];   // [d][kv] swizzled

  bf16x8 qf[4];
  {
    const unsigned short* qp = Q + base + (size_t)qq*64;
    #pragma unroll
    for (int s=0;s<4;s++) qf[s] = *(const bf16x8*)(qp + s*16 + hi*8);
  }

  f32x16 oacc[2];
  #pragma unroll
  for (int dt=0;dt<2;dt++)
    #pragma unroll
    for (int r=0;r<16;r++) oacc[dt][r] = 0.f;
  float m_i = -INFINITY, l_i = 0.f;

  const int NT = 2*qt + 2;

  auto stage = [&](int kt, int half){
    const int kv0 = kt*64;
    #pragma unroll
    for (int i=0;i<2;i++){
      int c = tid + i*256;
      int row = c>>3;
      int kc = (c&7) ^ (row&7);
      gload_lds16(Kg + base + (size_t)(kv0+row)*64 + kc*8, &Ks[half][0] + c*8);
      gload_lds16(Vt + base + (size_t)row*2048 + kv0 + kc*8, &Vs[half][0] + c*8);
    }
  };

  stage(0, 0);
  __syncthreads();

  for (int kt=0; kt<NT; kt++){
    const int cur = kt & 1;
    if (kt+1 < NT) stage(kt+1, cur^1);
    const int kv0 = kt*64;

    f32x16 sacc[2];
    #pragma unroll
    for (int kvt=0;kvt<2;kvt++)
      #pragma unroll
      for (int r=0;r<16;r++) sacc[kvt][r] = 0.f;

    __builtin_amdgcn_s_setprio(1);
    #pragma unroll
    for (int kvt=0;kvt<2;kvt++){
      int row = kvt*32 + lq;
      const char* kb = (const char*)&Ks[cur][0] + row*128;
      int swz = (row&7)<<4;
      #pragma unroll
      for (int s=0;s<4;s++){
        bf16x8 kf = *(const bf16x8*)(kb + ((s*32 + hi*16) ^ swz));
        sacc[kvt] = __builtin_amdgcn_mfma_f32_32x32x16_bf16(kf, qf[s], sacc[kvt], 0,0,0);
      }
    }
    __builtin_amdgcn_s_setprio(0);

    #pragma unroll
    for (int kvt=0;kvt<2;kvt++){
      if (kv0 + kvt*32 + 31 > q0 + w*32){
        #pragma unroll
        for (int r=0;r<16;r++){
          int kvv = kv0 + kvt*32 + (r&3) + 8*(r>>2) + 4*hi;
          if (kvv > qq) sacc[kvt][r] = -1e30f;
        }
      }
    }

    float mt = sacc[0][0];
    #pragma unroll
    for (int kvt=0;kvt<2;kvt++)
      #pragma unroll
      for (int r=0;r<16;r++) mt = fmaxf(mt, sacc[kvt][r]);
    mt = fmaxf(mt, __shfl_xor(mt, 32));

    if (__any(mt > m_i + 8.f)){
      float mn = fmaxf(m_i, mt);
      float sc = EXP2(m_i - mn);
      m_i = mn;
      l_i *= sc;
      #pragma unroll
      for (int dt=0;dt<2;dt++)
        #pragma unroll
        for (int r=0;r<16;r++) oacc[dt][r] *= sc;
    }
    float rs = 0.f;
    #pragma unroll
    for (int kvt=0;kvt<2;kvt++)
      #pragma unroll
      for (int r=0;r<16;r++){
        float pv = EXP2(sacc[kvt][r] - m_i);
        sacc[kvt][r] = pv;
        rs += pv;
      }
    rs += __shfl_xor(rs, 32);
    l_i += rs;

    unsigned pa[8], pb[8], sa[8], sb[8];
    #pragma unroll
    for (int g=0; g<8; g++){
      int kvt = g>>2, gl = g&3;
      pa[g] = cvt_pk_bf16(sacc[kvt][4*gl+0], sacc[kvt][4*gl+1]);
      pb[g] = cvt_pk_bf16(sacc[kvt][4*gl+2], sacc[kvt][4*gl+3]);
      sa[g] = __shfl_xor(pa[g], 32);
      sb[g] = __shfl_xor(pb[g], 32);
    }
    bf16x8 pfrag[4];
    #pragma unroll
    for (int s=0;s<4;s++){
      int g0 = (s>>1)*4 + 2*(s&1);
      unsigned w0 = hi ? sa[g0+1] : pa[g0];
      unsigned w1 = hi ? sb[g0+1] : pb[g0];
      unsigned w2 = hi ? pa[g0+1] : sa[g0];
      unsigned w3 = hi ? pb[g0+1] : sb[g0];
      pfrag[s] = mk8(w0, w1, w2, w3);
    }

    __builtin_amdgcn_s_setprio(1);
    #pragma unroll
    for (int dt=0;dt<2;dt++){
      int row = dt*32 + lq;
      const char* vb = (const char*)&Vs[cur][0] + row*128;
      int swz = (row&7)<<4;
      #pragma unroll
      for (int s=0;s<4;s++){
        bf16x8 vf = *(const bf16x8*)(vb + ((s*32 + hi*16) ^ swz));
        oacc[dt] = __builtin_amdgcn_mfma_f32_32x32x16_bf16(vf, pfrag[s], oacc[dt], 0,0,0);
      }
    }
    __builtin_amdgcn_s_setprio(0);

    __syncthreads();
  }

  unsigned short* Es = &Ks[0][0] + w*2048;
  float inv = 1.0f / l_i;
  {
    char* eb = (char*)Es + lq*128;
    int swz = (lq&7)<<4;
    #pragma unroll
    for (int dt=0;dt<2;dt++)
      #pragma unroll
      for (int g=0;g<4;g++){
        int d0 = dt*32 + 8*g + 4*hi;
        unsigned u0 = cvt_pk_bf16(oacc[dt][4*g+0]*inv, oacc[dt][4*g+1]*inv);
        unsigned u1 = cvt_pk_bf16(oacc[dt][4*g+2]*inv, oacc[dt][4*g+3]*inv);
        *(unsigned*)(eb + ((d0*2    ) ^ swz)) = u0;
        *(unsigned*)(eb + ((d0*2 + 4) ^ swz)) = u1;
      }
  }
  const int b = bh>>4, h = bh&15;
  {
    const char* rb = (const char*)Es + lq*128;
    int swz = (lq&7)<<4;
    unsigned short* op = AO + ((size_t)b*2048 + (q0 + w*32 + lq))*1024 + h*64 + hi*32;
    #pragma unroll
    for (int j=0;j<2;j++){
      bf16x8 v = *(const bf16x8*)(rb + ((hi*64 + j*16) ^ swz));
      *(bf16x8*)(op + j*8) = v;
    }
    #pragma unroll
    for (int j=2;j<4;j++){
      bf16x8 v = *(const bf16x8*)(rb + ((hi*64 + j*16) ^ swz));
      *(bf16x8*)(op + j*8) = v;
    }
  }
}

// ---------------------------------------------------------------------------
// Kernel 3: output projection — same depth-2 counted-vmcnt structure.
// fp32 out + bias.
// ---------------------------------------------------------------------------
__global__ __launch_bounds__(256, 3) void proj_out_kernel(
  const unsigned short* __restrict__ A, const unsigned short* __restrict__ B,
  const float* __restrict__ Bb, float* __restrict__ Out)
{
  const int L = blockIdx.x;             // 256 blocks
  const int xcd = L & 7, g = L >> 3;
  const int tm = xcd*4 + (g>>3);
  const int tn = g & 7;
  const int m0 = tm*128, n0 = tn*128;
  const int tid = threadIdx.x;
  const int w = tid>>6, l = tid&63;
  const int wr = w>>1, wc = w&1;
  const int lg = l>>4, lr = l&15;

  __shared__ unsigned short As[3][4096];
  __shared__ unsigned short Bs[3][4096];

  f32x4 acc[4][4];
  #pragma unroll
  for (int i=0;i<4;i++)
    #pragma unroll
    for (int j=0;j<4;j++){ f32x4 z = {0.f,0.f,0.f,0.f}; acc[i][j] = z; }

  const int srow = l>>2;
  const int schk = (l&3) ^ (srow&3);
  auto stage = [&](int h, int buf){
    const int kt = h*32;
    #pragma unroll
    for (int i=0;i<2;i++){
      int rbase = w*32 + i*16;
      gload_lds16(A + (size_t)(m0+rbase+srow)*1024 + kt + schk*8, &As[buf][0] + rbase*32);
      gload_lds16(B + (size_t)(n0+rbase+srow)*1024 + kt + schk*8, &Bs[buf][0] + rbase*32);
    }
  };

  stage(0, 0);
  stage(1, 1);

  const int sca = (lg ^ (lr&3)) << 4;
  int cur = 0;
  for (int h=0; h<32; ++h){
    if (h < 31) asm volatile("s_waitcnt vmcnt(4)" ::: "memory");
    else        asm volatile("s_waitcnt vmcnt(0)" ::: "memory");
    __builtin_amdgcn_s_barrier();
    __builtin_amdgcn_sched_barrier(0);
    if (h < 30){
      int nb = cur + 2; if (nb >= 3) nb -= 3;
      stage(h+2, nb);
    }

    bf16x8 af[4], bfr[4];
    #pragma unroll
    for (int f=0;f<4;f++){
      af[f]  = *(const bf16x8*)((const char*)&As[cur][0] + (wr*64 + f*16 + lr)*64 + sca);
      bfr[f] = *(const bf16x8*)((const char*)&Bs[cur][0] + (wc*64 + f*16 + lr)*64 + sca);
    }
    #pragma unroll
    for (int fr=0;fr<4;fr++)
      #pragma unroll
      for (int fc=0;fc<4;fc++)
        acc[fr][fc] = __builtin_amdgcn_mfma_f32_16x16x32_bf16(af[fr], bfr[fc], acc[fr][fc], 0,0,0);

    cur = (cur==2) ? 0 : cur+1;
  }

  #pragma unroll
  for (int fc=0;fc<4;fc++){
    int n = n0 + wc*64 + fc*16 + lr;
    float bias = Bb[n];
    #pragma unroll
    for (int fr=0;fr<4;fr++){
      #pragma unroll
      for (int r=0;r<4;r++){
        int m = m0 + wr*64 + fr*16 + lg*4 + r;
        Out[(size_t)m*1024 + n] = acc[fr][fc][r] + bias;
      }
    }
  }
}

// ---------------------------------------------------------------------------
extern "C" void kernel_launch(void* const* d_in, const int* in_sizes, int n_in,
                              void* d_out, int out_size, void* d_ws, size_t ws_size,
                              hipStream_t stream)
{
  const float* Xq = (const float*)d_in[0];
  const float* Xk = (const float*)d_in[1];
  const float* Xv = (const float*)d_in[2];
  // d_in[3] = mask (causal, static) — unused
  const float* Wq = (const float*)d_in[4];
  const float* bq = (const float*)d_in[5];
  const float* Wk = (const float*)d_in[6];
  const float* bk = (const float*)d_in[7];
  const float* Wv = (const float*)d_in[8];
  const float* bv = (const float*)d_in[9];
  const float* Wo = (const float*)d_in[10];
  const float* bo = (const float*)d_in[11];

  unsigned short* ws  = (unsigned short*)d_ws;
  unsigned short* Xb  = ws;
  unsigned short* Wb  = ws + 12582912;
  unsigned short* Qw  = ws + 16777216;
  unsigned short* Kw  = ws + 20971520;
  unsigned short* Vw  = ws + 25165824;
  unsigned short* AOw = ws + 29360128;
  float* out = (float*)d_out;

  convert_kernel<<<dim3(512,7), 256, 0, stream>>>(Xq,Xk,Xv,Wq,Wk,Wv,Wo, ws);
  proj_qkv_kernel<<<768, 256, 0, stream>>>(Xb, Wb, bq,bk,bv, Qw,Kw,Vw);
  attn_kernel<<<512, 256, 0, stream>>>(Qw,Kw,Vw,AOw);
  proj_out_kernel<<<256, 256, 0, stream>>>(AOw, Wb + 3*1048576, bo, out);
}